// Round 2
// baseline (1801.431 us; speedup 1.0000x reference)
//
#include <hip/hip_runtime.h>
#include <math.h>

// ---------------------------------------------------------------- constants
#define BB 8
#define TT 2048
#define DV_ 1024
#define DA_ 128
#define D1_ 512
#define D2_ 128
#define DH_ 257
#define DHP 272            // padded (zeros) to 16-multiple for BK=16 GEMM
#define DG_ 128
#define MTOT (BB*TT)       // 16384 rows
#define NPX ((size_t)MTOT*DHP)

#define NEGS 0.01f
#define INV_E 0.36787944117144233f

// gap swizzle for B-tile LDS: insert 4-word gap every 32 words ->
// 16 b128 addresses/wave land 2-per-bank-group (free) instead of 4-way.
#define SWZ(c) ((c) + ((((c) >> 5)) << 2))
#define BST 144            // swizzled row stride (max SWZ(127)=139)
#define AST 132            // A-tile row stride (reads are broadcast-free)

// workspace layout (float offsets)
static const size_t o_px  = 0;                          // px [16384][272]
static const size_t o_acc = NPX;                        // corrections -> Y1
static const size_t o_A   = 2*NPX;                      // C1 [16384][512]; later Y2 [16384][272]
static const size_t o_C2  = o_A + (size_t)MTOT*D1_;     // C2 [16384][128]
static const size_t o_S   = o_C2 + (size_t)MTOT*128;    // S  [8][272]
static const size_t o_den = o_S + BB*DHP;               // den [16384]
static const size_t o_g1  = o_den + MTOT;               // gw1 padded [272][128]
static const size_t o_g2  = o_g1 + DHP*DG_;             // gw2 padded [272][128]
// x1/x2f overwrite the px region (px dead after k_y1 + k_band)

__device__ __forceinline__ float diag_w() {
    // identical fp32 ops to the generic path evaluated at xy == 1.0f
    float dd = logf(1.0f + sqrtf(1.0f*1.0f - 1.0f + 1e-7f));
    dd = fminf(fmaxf(dd, 1e-6f), 200.0f);
    float x2 = expf(-dd);
    return expf(x2) - 1.0f;
}

// ---------------------------------------------------------------- utilities
__global__ void k_zero(float* __restrict__ p, size_t n) {
    size_t i = (size_t)blockIdx.x * 256 + threadIdx.x;
    size_t stride = (size_t)gridDim.x * 256;
    for (; i < n; i += stride) p[i] = 0.f;
}

__global__ void k_den_init(float* __restrict__ den, const int* __restrict__ seq) {
    int r = blockIdx.x * 256 + threadIdx.x;   // 16384 total
    den[r] = (float)seq[r >> 11] + diag_w();
}

__global__ void k_padgw(const float* __restrict__ g, float* __restrict__ gp) {
    int i = blockIdx.x * 256 + threadIdx.x;   // DHP*DG total
    if (i < DHP * DG_) gp[i] = (i < DH_ * DG_) ? g[i] : 0.f;
}

// ------------------------------------------------- 128x128 GEMM core macros
// loads: lr = tid>>2 (row within tile, +0/+64), lk = (tid&3)*4 (k offset)
#define STORE_A(v0, v1) \
    As[lk+0][lr]=v0.x; As[lk+1][lr]=v0.y; As[lk+2][lr]=v0.z; As[lk+3][lr]=v0.w; \
    As[lk+0][lr+64]=v1.x; As[lk+1][lr+64]=v1.y; As[lk+2][lr+64]=v1.z; As[lk+3][lr+64]=v1.w;
#define STORE_B(v0, v1) \
    Bs[lk+0][SWZ(lr)]=v0.x; Bs[lk+1][SWZ(lr)]=v0.y; Bs[lk+2][SWZ(lr)]=v0.z; Bs[lk+3][SWZ(lr)]=v0.w; \
    Bs[lk+0][SWZ(lr+64)]=v1.x; Bs[lk+1][SWZ(lr+64)]=v1.y; Bs[lk+2][SWZ(lr+64)]=v1.z; Bs[lk+3][SWZ(lr+64)]=v1.w;
#define INNER16(acc) \
    _Pragma("unroll") \
    for (int k = 0; k < 16; ++k) { \
        float4 aA = *(const float4*)&As[k][ty*8]; \
        float4 aB = *(const float4*)&As[k][ty*8+4]; \
        float4 bA = *(const float4*)&Bs[k][SWZ(tx*8)]; \
        float4 bB = *(const float4*)&Bs[k][SWZ(tx*8)+4]; \
        float ar[8] = {aA.x,aA.y,aA.z,aA.w,aB.x,aB.y,aB.z,aB.w}; \
        float br[8] = {bA.x,bA.y,bA.z,bA.w,bB.x,bB.y,bB.z,bB.w}; \
        _Pragma("unroll") \
        for (int ii = 0; ii < 8; ++ii) \
            _Pragma("unroll") \
            for (int jj = 0; jj < 8; ++jj) \
                acc[ii][jj] += ar[ii] * br[jj]; \
    }

// ------------------------------------------------- C = leaky(A*W^T + b)
// A [M x K] row stride lda ; W [N x K] row-major ; C [M x N]
__global__ __launch_bounds__(256, 4) void gemm128_nt_leaky(
    const float* __restrict__ A, int lda,
    const float* __restrict__ W, const float* __restrict__ bias,
    float* __restrict__ C, int N, int K)
{
    __shared__ float As[16][AST];
    __shared__ float Bs[16][BST];
    const int row0 = blockIdx.y * 128, col0 = blockIdx.x * 128;
    const int tid = threadIdx.x;
    const int lr = tid >> 2, lk = (tid & 3) * 4;
    const int tx = tid & 15, ty = tid >> 4;
    const float* Ar0 = A + (size_t)(row0 + lr) * lda + lk;
    const float* Ar1 = A + (size_t)(row0 + lr + 64) * lda + lk;
    const float* Wr0 = W + (size_t)(col0 + lr) * K + lk;
    const float* Wr1 = W + (size_t)(col0 + lr + 64) * K + lk;
    float4 a0 = *(const float4*)(Ar0);
    float4 a1 = *(const float4*)(Ar1);
    float4 w0 = *(const float4*)(Wr0);
    float4 w1 = *(const float4*)(Wr1);
    float acc[8][8] = {};
    for (int k0 = 16; ; k0 += 16) {
        __syncthreads();
        STORE_A(a0, a1)
        STORE_B(w0, w1)
        __syncthreads();
        bool more = (k0 < K);
        if (more) {
            a0 = *(const float4*)(Ar0 + k0);
            a1 = *(const float4*)(Ar1 + k0);
            w0 = *(const float4*)(Wr0 + k0);
            w1 = *(const float4*)(Wr1 + k0);
        }
        INNER16(acc)
        if (!more) break;
    }
#pragma unroll
    for (int ii = 0; ii < 8; ++ii) {
        int m = row0 + ty*8 + ii;
        float* crow = C + (size_t)m * N + col0 + tx*8;
#pragma unroll
        for (int jj = 0; jj < 8; ++jj) {
            float v = acc[ii][jj] + bias[col0 + tx*8 + jj];
            crow[jj] = (v >= 0.f) ? v : NEGS * v;
        }
    }
}

// ------------------------------------------------- xy GEMM (symmetric, upper tri)
// dot = px_i . px_j over 272 (pads zero); xy = 2 c_i c_j - dot.
// pairs i<j, both valid, x2>0.8: both rows get w = e^x2 - 1.
__global__ __launch_bounds__(256, 4) void k_xy128(
    const float* __restrict__ px, const int* __restrict__ seq,
    float* __restrict__ den, float* __restrict__ accb)
{
    const int b = blockIdx.z;
    const int bx = blockIdx.x, by = blockIdx.y;
    if (bx < by) return;                       // strictly lower-tri blocks skipped
    const int nb = seq[b];
    const int row0 = by * 128, col0 = bx * 128;
    if (row0 >= nb || col0 >= nb) return;
    const float* base = px + (size_t)b * TT * DHP;
    __shared__ float As[16][AST];
    __shared__ float Bs[16][BST];
    const int tid = threadIdx.x;
    const int lr = tid >> 2, lk = (tid & 3) * 4;
    const int tx = tid & 15, ty = tid >> 4;
    const float* Ar0 = base + (size_t)(row0 + lr) * DHP + lk;
    const float* Ar1 = base + (size_t)(row0 + lr + 64) * DHP + lk;
    const float* Br0 = base + (size_t)(col0 + lr) * DHP + lk;
    const float* Br1 = base + (size_t)(col0 + lr + 64) * DHP + lk;
    float4 a0 = *(const float4*)(Ar0);
    float4 a1 = *(const float4*)(Ar1);
    float4 w0 = *(const float4*)(Br0);
    float4 w1 = *(const float4*)(Br1);
    float acc[8][8] = {};
    for (int k0 = 16; ; k0 += 16) {
        __syncthreads();
        STORE_A(a0, a1)
        STORE_B(w0, w1)
        __syncthreads();
        bool more = (k0 < DHP);
        if (more) {
            a0 = *(const float4*)(Ar0 + k0);
            a1 = *(const float4*)(Ar1 + k0);
            w0 = *(const float4*)(Br0 + k0);
            w1 = *(const float4*)(Br1 + k0);
        }
        INNER16(acc)
        if (!more) break;
    }
    float ci[8], cj[8];
#pragma unroll
    for (int t = 0; t < 8; ++t) {
        ci[t] = base[(size_t)(row0 + ty*8 + t) * DHP];
        cj[t] = base[(size_t)(col0 + tx*8 + t) * DHP];
    }
#pragma unroll
    for (int ii = 0; ii < 8; ++ii) {
        int i = row0 + ty*8 + ii;
        if (i >= nb) continue;
#pragma unroll
        for (int jj = 0; jj < 8; ++jj) {
            int j = col0 + tx*8 + jj;
            if (j <= i || j >= nb) continue;
            float xyv = 2.f * ci[ii] * cj[jj] - acc[ii][jj];
            float xym = fmaxf(xyv, 1.0f);
            // xym >= 1.026 => d >= 0.2266 => x2 <= 0.798 < 0.8: no correction
            if (xym < 1.026f) {
                float dd = logf(xym + sqrtf(xym * xym - 1.0f + 1e-7f));
                dd = fminf(fmaxf(dd, 1e-6f), 200.0f);
                float x2v = expf(-dd);
                if (x2v > 0.8f) {
                    float w = expf(x2v) - 1.0f;
                    atomicAdd(&den[b * TT + i], w);
                    atomicAdd(&den[b * TT + j], w);
                    const float* pi = base + (size_t)i * DHP;
                    const float* pj = base + (size_t)j * DHP;
                    float* ai = accb + ((size_t)(b * TT + i)) * DHP;
                    float* aj = accb + ((size_t)(b * TT + j)) * DHP;
                    for (int d = 0; d < DHP; ++d) {
                        atomicAdd(&ai[d], w * pj[d]);
                        atomicAdd(&aj[d], w * pi[d]);
                    }
                }
            }
        }
    }
}

// ------------------------------------------------- expmap0 (build px)
__global__ __launch_bounds__(256) void k_proj(
    const float* __restrict__ C2, const float* __restrict__ inputs,
    float* __restrict__ px)
{
    const int r = blockIdx.x;
    const int tid = threadIdx.x;
    float v = (tid < 128) ? C2[(size_t)r * 128 + tid]
                          : inputs[(size_t)r * 1152 + 1024 + (tid - 128)];
    float sq = v * v;
#pragma unroll
    for (int o = 32; o > 0; o >>= 1) sq += __shfl_down(sq, o, 64);
    __shared__ float wred[4];
    __shared__ float cs[2];
    if ((tid & 63) == 0) wred[tid >> 6] = sq;
    __syncthreads();
    if (tid == 0) {
        float n2 = fmaxf(wred[0] + wred[1] + wred[2] + wred[3], 1e-12f);
        float n = sqrtf(n2);
        cs[0] = coshf(n);
        cs[1] = sinhf(n) / n;
    }
    __syncthreads();
    float s = cs[1];
    px[(size_t)r * DHP + 1 + tid] = s * v;
    if (tid == 0) px[(size_t)r * DHP] = cs[0];
    if (tid < DHP - DH_) px[(size_t)r * DHP + DH_ + tid] = 0.f;  // 15 pad zeros
}

// ------------------------------------------------- per-batch valid column sum
__global__ __launch_bounds__(256) void k_ssum(
    const float* __restrict__ px, const int* __restrict__ seq,
    float* __restrict__ S)
{
    const int b = blockIdx.x, chunk = blockIdx.y, tid = threadIdx.x;
    const int nb = seq[b];
    const int j0 = chunk * 128;
    const int j1 = (j0 + 128 < nb) ? j0 + 128 : nb;
    float a0 = 0.f, a1 = 0.f;
    const bool hasB = (tid < DHP - 256);
    for (int j = j0; j < j1; ++j) {
        const float* row = px + ((size_t)(b * TT + j)) * DHP;
        a0 += row[tid];
        if (hasB) a1 += row[256 + tid];
    }
    if (j1 > j0) {
        atomicAdd(&S[b * DHP + tid], a0);
        if (hasB) atomicAdd(&S[b * DHP + 256 + tid], a1);
    }
}

// ------------------------------------------------- Y1 = (S + corr + wd*px)/den
__global__ void k_y1(float* __restrict__ accb, const float* __restrict__ S,
                     const float* __restrict__ den, const int* __restrict__ seq,
                     const float* __restrict__ px)
{
    size_t idx = (size_t)blockIdx.x * 256 + threadIdx.x;
    if (idx >= NPX) return;
    int r = (int)(idx / DHP), d = (int)(idx % DHP);
    int b = r >> 11, i = r & (TT - 1);
    float out = 0.f;
    if (i < seq[b])
        out = (S[b * DHP + d] + accb[idx] + diag_w() * px[idx]) / den[r];
    accb[idx] = out;
}

// ------------------------------------------------- banded disadj @ px
__global__ __launch_bounds__(256) void k_band(
    const float* __restrict__ px, float* __restrict__ Y2)
{
    const int b = blockIdx.y;
    const int i0 = blockIdx.x * 8;
    const int tid = threadIdx.x;
    __shared__ float wtab[144];
    if (tid < 144) wtab[tid] = expf(-(float)tid * INV_E);
    __syncthreads();
    const int jlo = (i0 - 128 > 0) ? i0 - 128 : 0;
    const int jhi = (i0 + 7 + 128 < TT - 1) ? i0 + 7 + 128 : TT - 1;
    const float* base = px + (size_t)b * TT * DHP;
    const bool hasB = (tid < DHP - 256);
    float accA[8] = {}, accB[8] = {};
    for (int j = jlo; j <= jhi; ++j) {
        float pa = base[(size_t)j * DHP + tid];
        float pb = hasB ? base[(size_t)j * DHP + 256 + tid] : 0.f;
#pragma unroll
        for (int ii = 0; ii < 8; ++ii) {
            int dd = i0 + ii - j; dd = (dd < 0) ? -dd : dd;
            float w = wtab[dd];
            accA[ii] += w * pa;
            accB[ii] += w * pb;
        }
    }
#pragma unroll
    for (int ii = 0; ii < 8; ++ii) {
        Y2[((size_t)(b * TT + i0 + ii)) * DHP + tid] = accA[ii];
        if (hasB) Y2[((size_t)(b * TT + i0 + ii)) * DHP + 256 + tid] = accB[ii];
    }
}

// ------------------------------------------------- GEMM: C = leaky(A*G)  (NN)
// A [M x 272] row stride DHP ; G [272 x 128] row-major ; C [M x 128]
__global__ __launch_bounds__(256) void gemm_nn_leaky(
    const float* __restrict__ A, const float* __restrict__ G,
    float* __restrict__ C)
{
    __shared__ float As[8][68];
    __shared__ float Gs[8][68];
    const int row0 = blockIdx.y * 64, col0 = blockIdx.x * 64;
    const int tid = threadIdx.x;
    const int tx = tid & 15, ty = tid >> 4;
    const int lr = tid >> 2, lc = (tid & 3) * 2;
    const int gk = tid >> 6, gc = tid & 63;
    float acc[4][4] = {};
    for (int k0 = 0; k0 < DHP; k0 += 8) {
        float2 av = *(const float2*)(A + (size_t)(row0 + lr) * DHP + k0 + lc);
        float g0 = G[(size_t)(k0 + gk) * DG_ + col0 + gc];
        float g1 = G[(size_t)(k0 + gk + 4) * DG_ + col0 + gc];
        __syncthreads();
        As[lc+0][lr] = av.x; As[lc+1][lr] = av.y;
        Gs[gk][gc] = g0; Gs[gk+4][gc] = g1;
        __syncthreads();
#pragma unroll
        for (int k = 0; k < 8; ++k) {
            float4 a = *(const float4*)&As[k][ty*4];
            float4 g = *(const float4*)&Gs[k][tx*4];
            acc[0][0]+=a.x*g.x; acc[0][1]+=a.x*g.y; acc[0][2]+=a.x*g.z; acc[0][3]+=a.x*g.w;
            acc[1][0]+=a.y*g.x; acc[1][1]+=a.y*g.y; acc[1][2]+=a.y*g.z; acc[1][3]+=a.y*g.w;
            acc[2][0]+=a.z*g.x; acc[2][1]+=a.z*g.y; acc[2][2]+=a.z*g.z; acc[2][3]+=a.z*g.w;
            acc[3][0]+=a.w*g.x; acc[3][1]+=a.w*g.y; acc[3][2]+=a.w*g.z; acc[3][3]+=a.w*g.w;
        }
    }
#pragma unroll
    for (int ii = 0; ii < 4; ++ii)
#pragma unroll
        for (int jj = 0; jj < 4; ++jj) {
            int m = row0 + ty*4 + ii, n = col0 + tx*4 + jj;
            float v = acc[ii][jj];
            C[(size_t)m * DG_ + n] = (v >= 0.f) ? v : NEGS * v;
        }
}

// ------------------------------------------------- frame_prob
__global__ __launch_bounds__(256) void k_frame(
    const float* __restrict__ x1, const float* __restrict__ x2f,
    const float* __restrict__ cls_w, const float* __restrict__ cls_b,
    float* __restrict__ dout)
{
    const int r = blockIdx.x * 4 + (threadIdx.x >> 6);
    const int lane = threadIdx.x & 63;
    float s = 0.f;
#pragma unroll
    for (int t = 0; t < 2; ++t) {
        int g = lane + t * 64;
        float cw1 = cls_w[g];
        if (g == 0) cw1 = -cw1;      // signs: only dim 0 negated
        s += x1[(size_t)r * DG_ + g] * cw1;
        s += x2f[(size_t)r * DG_ + g] * cls_w[DG_ + g];
    }
#pragma unroll
    for (int o = 32; o > 0; o >>= 1) s += __shfl_down(s, o, 64);
    if (lane == 0) dout[8 + r] = 2.0f + 2.0f * s + cls_b[0];
}

// ------------------------------------------------- top-k MIL (bitonic sort)
__global__ __launch_bounds__(256) void k_clas(
    const int* __restrict__ seq, float* __restrict__ dout)
{
    __shared__ float s[TT];
    const int b = blockIdx.x, tid = threadIdx.x;
    const int nb = seq[b];
    for (int t = tid; t < TT; t += 256)
        s[t] = (t < nb) ? dout[8 + b * TT + t] : -1e30f;
    __syncthreads();
    for (int k = 2; k <= TT; k <<= 1)
        for (int j = k >> 1; j > 0; j >>= 1) {
            for (int i = tid; i < TT; i += 256) {
                int ixj = i ^ j;
                if (ixj > i) {
                    float a = s[i], c = s[ixj];
                    bool descBlk = ((i & k) == 0);
                    if (descBlk ? (a < c) : (a > c)) { s[i] = c; s[ixj] = a; }
                }
            }
            __syncthreads();
        }
    const int kk = nb / 16 + 1;
    float part = 0.f;
    for (int t = tid; t < kk; t += 256) part += s[t];
#pragma unroll
    for (int o = 32; o > 0; o >>= 1) part += __shfl_down(part, o, 64);
    __shared__ float wred[4];
    if ((tid & 63) == 0) wred[tid >> 6] = part;
    __syncthreads();
    if (tid == 0) {
        float mil = (wred[0] + wred[1] + wred[2] + wred[3]) / (float)kk;
        dout[b] = 1.f / (1.f + expf(-mil));
    }
}

// ---------------------------------------------------------------- launch
extern "C" void kernel_launch(void* const* d_in, const int* in_sizes, int n_in,
                              void* d_out, int out_size, void* d_ws, size_t ws_size,
                              hipStream_t stream) {
    (void)in_sizes; (void)n_in; (void)out_size; (void)ws_size;
    const float* inputs = (const float*)d_in[0];
    const int*   seq    = (const int*)d_in[1];
    const float* w1     = (const float*)d_in[2];
    const float* b1     = (const float*)d_in[3];
    const float* w2     = (const float*)d_in[4];
    const float* b2     = (const float*)d_in[5];
    const float* gw1    = (const float*)d_in[6];
    const float* gw2    = (const float*)d_in[7];
    const float* cls_w  = (const float*)d_in[8];
    const float* cls_b  = (const float*)d_in[9];
    float* dout = (float*)d_out;
    float* ws = (float*)d_ws;

    float* px  = ws + o_px;
    float* accb= ws + o_acc;   // corrections -> Y1
    float* C1  = ws + o_A;
    float* Y2  = ws + o_A;
    float* C2  = ws + o_C2;
    float* S   = ws + o_S;
    float* den = ws + o_den;
    float* g1p = ws + o_g1;
    float* g2p = ws + o_g2;
    float* x1  = ws + o_px;                      // px dead after k_y1/k_band
    float* x2f = ws + o_px + (size_t)MTOT * 128;

    // init (ws is re-poisoned before every launch)
    k_zero<<<4096, 256, 0, stream>>>(accb, NPX);
    k_zero<<<16, 256, 0, stream>>>(S, (size_t)BB * DHP);
    k_den_init<<<MTOT / 256, 256, 0, stream>>>(den, seq);
    k_padgw<<<(DHP * DG_ + 255) / 256, 256, 0, stream>>>(gw1, g1p);
    k_padgw<<<(DHP * DG_ + 255) / 256, 256, 0, stream>>>(gw2, g2p);

    // MLP
    gemm128_nt_leaky<<<dim3(D1_ / 128, MTOT / 128), 256, 0, stream>>>(
        inputs, 1152, w1, b1, C1, D1_, DV_);
    gemm128_nt_leaky<<<dim3(D2_ / 128, MTOT / 128), 256, 0, stream>>>(
        C1, D1_, w2, b2, C2, D2_, D1_);

    // expmap0
    k_proj<<<MTOT, 256, 0, stream>>>(C2, inputs, px);

    // valid column sums
    k_ssum<<<dim3(BB, TT / 128), 256, 0, stream>>>(px, seq, S);

    // Lorentz similarity, upper triangle only + sparse softmax corrections
    k_xy128<<<dim3(TT / 128, TT / 128, BB), 256, 0, stream>>>(px, seq, den, accb);

    // Y1 = (S + corr + diag)/den, zero for invalid rows
    k_y1<<<(int)(NPX / 256), 256, 0, stream>>>(accb, S, den, seq, px);

    // banded disadj @ px
    k_band<<<dim3(TT / 8, BB), 256, 0, stream>>>(px, Y2);

    // graph-conv projections (x1/x2f overwrite px region)
    gemm_nn_leaky<<<dim3(DG_ / 64, MTOT / 64), 256, 0, stream>>>(accb, g1p, x1);
    gemm_nn_leaky<<<dim3(DG_ / 64, MTOT / 64), 256, 0, stream>>>(Y2, g2p, x2f);

    // frame_prob + MIL
    k_frame<<<MTOT / 4, 256, 0, stream>>>(x1, x2f, cls_w, cls_b, dout);
    k_clas<<<BB, 256, 0, stream>>>(seq, dout);
}

// Round 3
// 1430.323 us; speedup vs baseline: 1.2595x; 1.2595x over previous
//
#include <hip/hip_runtime.h>
#include <math.h>

// ---------------------------------------------------------------- constants
#define BB 8
#define TT 2048
#define DV_ 1024
#define DA_ 128
#define D1_ 512
#define D2_ 128
#define DH_ 257
#define DHP 288            // padded (zeros): divisible by 32 for MFMA K-chunks
#define DG_ 128
#define MTOT (BB*TT)       // 16384 rows
#define NPX ((size_t)MTOT*DHP)

#define NEGS 0.01f
#define INV_E 0.36787944117144233f

// gap swizzle for B-tile LDS: insert 4-word gap every 32 words
#define SWZ(c) ((c) + ((((c) >> 5)) << 2))
#define BST 140            // 140%32=12 -> store groups lk*{12} land 2-way (free); 144 was 4-way
#define AST 132            // 132%32=4  -> 2-way stores; reads broadcast

// workspace layout (float offsets) — aliased to stay ~72 MB
//  o_px  : px fp32 [16384][288]                    (live: k_proj .. k_band; then x1/x2f)
//  o_acc : C2 [16384][128] (MLP2 out) -> zeroed -> accb corrections -> Y1
//  o_A   : C1 [16384][512] -> pxb bf16 [16384][288] -> Y2 [16384][288]
static const size_t o_px  = 0;
static const size_t o_acc = NPX;                        // 4,718,592
static const size_t o_A   = 2*NPX;                      // 9,437,184
static const size_t o_S   = o_A + (size_t)MTOT*D1_;     // 17,825,792
static const size_t o_den = o_S + BB*DHP;
static const size_t o_g1  = o_den + MTOT;
static const size_t o_g2  = o_g1 + DHP*DG_;

typedef __attribute__((ext_vector_type(8))) __bf16 bf16x8;
typedef __attribute__((ext_vector_type(4))) float f32x4;

__device__ __forceinline__ float diag_w() {
    // identical fp32 ops to the generic path evaluated at xy == 1.0f
    float dd = logf(1.0f + sqrtf(1.0f*1.0f - 1.0f + 1e-7f));
    dd = fminf(fmaxf(dd, 1e-6f), 200.0f);
    float x2 = expf(-dd);
    return expf(x2) - 1.0f;
}

__device__ __forceinline__ unsigned short f2bf(float f) {
    unsigned int u = __float_as_uint(f);
    u += 0x7FFFu + ((u >> 16) & 1u);   // RNE
    return (unsigned short)(u >> 16);
}

// ---------------------------------------------------------------- utilities
__global__ void k_zero(float* __restrict__ p, size_t n) {
    size_t i = (size_t)blockIdx.x * 256 + threadIdx.x;
    size_t stride = (size_t)gridDim.x * 256;
    for (; i < n; i += stride) p[i] = 0.f;
}

__global__ void k_den_init(float* __restrict__ den, const int* __restrict__ seq) {
    int r = blockIdx.x * 256 + threadIdx.x;   // 16384 total
    den[r] = (float)seq[r >> 11] + diag_w();
}

__global__ void k_padgw(const float* __restrict__ g, float* __restrict__ gp) {
    int i = blockIdx.x * 256 + threadIdx.x;   // DHP*DG total
    if (i < DHP * DG_) gp[i] = (i < DH_ * DG_) ? g[i] : 0.f;
}

// ------------------------------------------------- 128x128 fp32 GEMM core
#define STORE_A(v0, v1) \
    As[lk+0][lr]=v0.x; As[lk+1][lr]=v0.y; As[lk+2][lr]=v0.z; As[lk+3][lr]=v0.w; \
    As[lk+0][lr+64]=v1.x; As[lk+1][lr+64]=v1.y; As[lk+2][lr+64]=v1.z; As[lk+3][lr+64]=v1.w;
#define STORE_B(v0, v1) \
    Bs[lk+0][SWZ(lr)]=v0.x; Bs[lk+1][SWZ(lr)]=v0.y; Bs[lk+2][SWZ(lr)]=v0.z; Bs[lk+3][SWZ(lr)]=v0.w; \
    Bs[lk+0][SWZ(lr+64)]=v1.x; Bs[lk+1][SWZ(lr+64)]=v1.y; Bs[lk+2][SWZ(lr+64)]=v1.z; Bs[lk+3][SWZ(lr+64)]=v1.w;
#define INNER16(acc) \
    _Pragma("unroll") \
    for (int k = 0; k < 16; ++k) { \
        float4 aA = *(const float4*)&As[k][ty*8]; \
        float4 aB = *(const float4*)&As[k][ty*8+4]; \
        float4 bA = *(const float4*)&Bs[k][SWZ(tx*8)]; \
        float4 bB = *(const float4*)&Bs[k][SWZ(tx*8)+4]; \
        float ar[8] = {aA.x,aA.y,aA.z,aA.w,aB.x,aB.y,aB.z,aB.w}; \
        float br[8] = {bA.x,bA.y,bA.z,bA.w,bB.x,bB.y,bB.z,bB.w}; \
        _Pragma("unroll") \
        for (int ii = 0; ii < 8; ++ii) \
            _Pragma("unroll") \
            for (int jj = 0; jj < 8; ++jj) \
                acc[ii][jj] += ar[ii] * br[jj]; \
    }

// C = leaky(A*W^T + b); A [M x K] stride lda; W [N x K]; no launch_bounds cap
// (r2 post-mortem: __launch_bounds__(256,4) clamped VGPR to 64 -> 64 accs spilled)
__global__ void gemm128_nt_leaky(
    const float* __restrict__ A, int lda,
    const float* __restrict__ W, const float* __restrict__ bias,
    float* __restrict__ C, int N, int K)
{
    __shared__ float As[16][AST];
    __shared__ float Bs[16][BST];
    const int row0 = blockIdx.y * 128, col0 = blockIdx.x * 128;
    const int tid = threadIdx.x;
    const int lr = tid >> 2, lk = (tid & 3) * 4;
    const int tx = tid & 15, ty = tid >> 4;
    const float* Ar0 = A + (size_t)(row0 + lr) * lda + lk;
    const float* Ar1 = A + (size_t)(row0 + lr + 64) * lda + lk;
    const float* Wr0 = W + (size_t)(col0 + lr) * K + lk;
    const float* Wr1 = W + (size_t)(col0 + lr + 64) * K + lk;
    float4 a0 = *(const float4*)(Ar0);
    float4 a1 = *(const float4*)(Ar1);
    float4 w0 = *(const float4*)(Wr0);
    float4 w1 = *(const float4*)(Wr1);
    float acc[8][8] = {};
    for (int k0 = 16; ; k0 += 16) {
        __syncthreads();
        STORE_A(a0, a1)
        STORE_B(w0, w1)
        __syncthreads();
        bool more = (k0 < K);
        if (more) {
            a0 = *(const float4*)(Ar0 + k0);
            a1 = *(const float4*)(Ar1 + k0);
            w0 = *(const float4*)(Wr0 + k0);
            w1 = *(const float4*)(Wr1 + k0);
        }
        INNER16(acc)
        if (!more) break;
    }
#pragma unroll
    for (int ii = 0; ii < 8; ++ii) {
        int m = row0 + ty*8 + ii;
        float* crow = C + (size_t)m * N + col0 + tx*8;
#pragma unroll
        for (int jj = 0; jj < 8; ++jj) {
            float v = acc[ii][jj] + bias[col0 + tx*8 + jj];
            crow[jj] = (v >= 0.f) ? v : NEGS * v;
        }
    }
}

// ------------------------------------------------- xy via bf16 MFMA (upper tri)
// Only observable effect: which pairs pass x2>0.8. Off-diag xy ~ 1e13 vs band
// [1,1.026]; bf16 error ~1e11 -> classification identical to fp32/f64.
__global__ __launch_bounds__(256) void k_xy_mfma(
    const unsigned short* __restrict__ pxb, const float* __restrict__ px,
    const int* __restrict__ seq, float* __restrict__ den, float* __restrict__ accb)
{
    const int b = blockIdx.z;
    const int bx = blockIdx.x, by = blockIdx.y;
    if (bx < by) return;
    const int nb = seq[b];
    const int row0 = by * 128, col0 = bx * 128;
    if (row0 >= nb || col0 >= nb) return;
    const int wave = threadIdx.x >> 6, lane = threadIdx.x & 63;
    const int r0 = row0 + (wave >> 1) * 64, c0 = col0 + (wave & 1) * 64;
    if (c0 + 63 < r0 || r0 >= nb || c0 >= nb) return;   // wave-uniform exits
    const unsigned short* base = pxb + (size_t)b * TT * DHP;
    const int q = lane >> 4, m = lane & 15;
    f32x4 acc[4][4];
#pragma unroll
    for (int a = 0; a < 4; ++a)
#pragma unroll
        for (int c = 0; c < 4; ++c) acc[a][c] = (f32x4){0.f, 0.f, 0.f, 0.f};
    for (int k0 = 0; k0 < DHP; k0 += 32) {
        bf16x8 af[4], bf[4];
#pragma unroll
        for (int t = 0; t < 4; ++t) {
            af[t] = *(const bf16x8*)(base + (size_t)(r0 + t*16 + m) * DHP + k0 + q*8);
            bf[t] = *(const bf16x8*)(base + (size_t)(c0 + t*16 + m) * DHP + k0 + q*8);
        }
#pragma unroll
        for (int mi = 0; mi < 4; ++mi)
#pragma unroll
            for (int nj = 0; nj < 4; ++nj)
                acc[mi][nj] = __builtin_amdgcn_mfma_f32_16x16x32_bf16(
                    af[mi], bf[nj], acc[mi][nj], 0, 0, 0);
    }
    const float* b32 = px + (size_t)b * TT * DHP;
    float cj[4], ci[4][4];
#pragma unroll
    for (int nj = 0; nj < 4; ++nj) cj[nj] = b32[(size_t)(c0 + nj*16 + m) * DHP];
#pragma unroll
    for (int mi = 0; mi < 4; ++mi)
#pragma unroll
        for (int t = 0; t < 4; ++t) ci[mi][t] = b32[(size_t)(r0 + mi*16 + q*4 + t) * DHP];
#pragma unroll
    for (int mi = 0; mi < 4; ++mi)
#pragma unroll
        for (int nj = 0; nj < 4; ++nj)
#pragma unroll
            for (int t = 0; t < 4; ++t) {
                int i = r0 + mi*16 + q*4 + t;
                int j = c0 + nj*16 + m;
                if (i < j && j < nb) {
                    float xyv = 2.f * ci[mi][t] * cj[nj] - acc[mi][nj][t];
                    float xym = fmaxf(xyv, 1.0f);
                    // xym >= 1.026 => x2 <= 0.798 < 0.8: no correction
                    if (xym < 1.026f) {
                        float dd = logf(xym + sqrtf(xym * xym - 1.0f + 1e-7f));
                        dd = fminf(fmaxf(dd, 1e-6f), 200.0f);
                        float x2v = expf(-dd);
                        if (x2v > 0.8f) {
                            float w = expf(x2v) - 1.0f;
                            atomicAdd(&den[b * TT + i], w);
                            atomicAdd(&den[b * TT + j], w);
                            const float* pi = b32 + (size_t)i * DHP;
                            const float* pj = b32 + (size_t)j * DHP;
                            float* ai = accb + ((size_t)(b * TT + i)) * DHP;
                            float* aj = accb + ((size_t)(b * TT + j)) * DHP;
                            for (int d = 0; d < DHP; ++d) {
                                atomicAdd(&ai[d], w * pj[d]);
                                atomicAdd(&aj[d], w * pi[d]);
                            }
                        }
                    }
                }
            }
}

// ------------------------------------------------- expmap0 (px fp32 + bf16)
__global__ __launch_bounds__(256) void k_proj(
    const float* __restrict__ C2, const float* __restrict__ inputs,
    float* __restrict__ px, unsigned short* __restrict__ pxb)
{
    const int r = blockIdx.x;
    const int tid = threadIdx.x;
    float v = (tid < 128) ? C2[(size_t)r * 128 + tid]
                          : inputs[(size_t)r * 1152 + 1024 + (tid - 128)];
    float sq = v * v;
#pragma unroll
    for (int o = 32; o > 0; o >>= 1) sq += __shfl_down(sq, o, 64);
    __shared__ float wred[4];
    __shared__ float cs[2];
    if ((tid & 63) == 0) wred[tid >> 6] = sq;
    __syncthreads();
    if (tid == 0) {
        float n2 = fmaxf(wred[0] + wred[1] + wred[2] + wred[3], 1e-12f);
        float n = sqrtf(n2);
        cs[0] = coshf(n);
        cs[1] = sinhf(n) / n;
    }
    __syncthreads();
    float sv = cs[1] * v;
    px[(size_t)r * DHP + 1 + tid] = sv;
    pxb[(size_t)r * DHP + 1 + tid] = f2bf(sv);
    if (tid == 0) {
        px[(size_t)r * DHP] = cs[0];
        pxb[(size_t)r * DHP] = f2bf(cs[0]);
    }
    if (tid < DHP - DH_) {   // 31 pad zeros
        px[(size_t)r * DHP + DH_ + tid] = 0.f;
        pxb[(size_t)r * DHP + DH_ + tid] = 0;
    }
}

// ------------------------------------------------- per-batch valid column sum
__global__ __launch_bounds__(256) void k_ssum(
    const float* __restrict__ px, const int* __restrict__ seq,
    float* __restrict__ S)
{
    const int b = blockIdx.x, chunk = blockIdx.y, tid = threadIdx.x;
    const int nb = seq[b];
    const int j0 = chunk * 128;
    const int j1 = (j0 + 128 < nb) ? j0 + 128 : nb;
    float a0 = 0.f, a1 = 0.f;
    const bool hasB = (tid < DHP - 256);
    for (int j = j0; j < j1; ++j) {
        const float* row = px + ((size_t)(b * TT + j)) * DHP;
        a0 += row[tid];
        if (hasB) a1 += row[256 + tid];
    }
    if (j1 > j0) {
        atomicAdd(&S[b * DHP + tid], a0);
        if (hasB) atomicAdd(&S[b * DHP + 256 + tid], a1);
    }
}

// ------------------------------------------------- Y1 = (S + corr + wd*px)/den
__global__ void k_y1(float* __restrict__ accb, const float* __restrict__ S,
                     const float* __restrict__ den, const int* __restrict__ seq,
                     const float* __restrict__ px)
{
    size_t idx = (size_t)blockIdx.x * 256 + threadIdx.x;
    if (idx >= NPX) return;
    int r = (int)(idx / DHP), d = (int)(idx % DHP);
    int b = r >> 11, i = r & (TT - 1);
    float out = 0.f;
    if (i < seq[b])
        out = (S[b * DHP + d] + accb[idx] + diag_w() * px[idx]) / den[r];
    accb[idx] = out;
}

// ------------------------------------------------- banded disadj @ px
__global__ __launch_bounds__(256) void k_band(
    const float* __restrict__ px, float* __restrict__ Y2)
{
    const int b = blockIdx.y;
    const int i0 = blockIdx.x * 8;
    const int tid = threadIdx.x;
    __shared__ float wtab[144];
    if (tid < 144) wtab[tid] = expf(-(float)tid * INV_E);
    __syncthreads();
    const int jlo = (i0 - 128 > 0) ? i0 - 128 : 0;
    const int jhi = (i0 + 7 + 128 < TT - 1) ? i0 + 7 + 128 : TT - 1;
    const float* base = px + (size_t)b * TT * DHP;
    const bool hasB = (tid < DHP - 256);
    float accA[8] = {}, accB[8] = {};
    for (int j = jlo; j <= jhi; ++j) {
        float pa = base[(size_t)j * DHP + tid];
        float pb = hasB ? base[(size_t)j * DHP + 256 + tid] : 0.f;
#pragma unroll
        for (int ii = 0; ii < 8; ++ii) {
            int dd = i0 + ii - j; dd = (dd < 0) ? -dd : dd;
            float w = wtab[dd];
            accA[ii] += w * pa;
            accB[ii] += w * pb;
        }
    }
#pragma unroll
    for (int ii = 0; ii < 8; ++ii) {
        Y2[((size_t)(b * TT + i0 + ii)) * DHP + tid] = accA[ii];
        if (hasB) Y2[((size_t)(b * TT + i0 + ii)) * DHP + 256 + tid] = accB[ii];
    }
}

// ------------------------------------------------- GEMM: C = leaky(A*G)  (NN)
__global__ __launch_bounds__(256) void gemm_nn_leaky(
    const float* __restrict__ A, const float* __restrict__ G,
    float* __restrict__ C)
{
    __shared__ float As[8][68];
    __shared__ float Gs[8][68];
    const int row0 = blockIdx.y * 64, col0 = blockIdx.x * 64;
    const int tid = threadIdx.x;
    const int tx = tid & 15, ty = tid >> 4;
    const int lr = tid >> 2, lc = (tid & 3) * 2;
    const int gk = tid >> 6, gc = tid & 63;
    float acc[4][4] = {};
    for (int k0 = 0; k0 < DHP; k0 += 8) {
        float2 av = *(const float2*)(A + (size_t)(row0 + lr) * DHP + k0 + lc);
        float g0 = G[(size_t)(k0 + gk) * DG_ + col0 + gc];
        float g1 = G[(size_t)(k0 + gk + 4) * DG_ + col0 + gc];
        __syncthreads();
        As[lc+0][lr] = av.x; As[lc+1][lr] = av.y;
        Gs[gk][gc] = g0; Gs[gk+4][gc] = g1;
        __syncthreads();
#pragma unroll
        for (int k = 0; k < 8; ++k) {
            float4 a = *(const float4*)&As[k][ty*4];
            float4 g = *(const float4*)&Gs[k][tx*4];
            acc[0][0]+=a.x*g.x; acc[0][1]+=a.x*g.y; acc[0][2]+=a.x*g.z; acc[0][3]+=a.x*g.w;
            acc[1][0]+=a.y*g.x; acc[1][1]+=a.y*g.y; acc[1][2]+=a.y*g.z; acc[1][3]+=a.y*g.w;
            acc[2][0]+=a.z*g.x; acc[2][1]+=a.z*g.y; acc[2][2]+=a.z*g.z; acc[2][3]+=a.z*g.w;
            acc[3][0]+=a.w*g.x; acc[3][1]+=a.w*g.y; acc[3][2]+=a.w*g.z; acc[3][3]+=a.w*g.w;
        }
    }
#pragma unroll
    for (int ii = 0; ii < 4; ++ii)
#pragma unroll
        for (int jj = 0; jj < 4; ++jj) {
            int m = row0 + ty*4 + ii, n = col0 + tx*4 + jj;
            float v = acc[ii][jj];
            C[(size_t)m * DG_ + n] = (v >= 0.f) ? v : NEGS * v;
        }
}

// ------------------------------------------------- frame_prob
__global__ __launch_bounds__(256) void k_frame(
    const float* __restrict__ x1, const float* __restrict__ x2f,
    const float* __restrict__ cls_w, const float* __restrict__ cls_b,
    float* __restrict__ dout)
{
    const int r = blockIdx.x * 4 + (threadIdx.x >> 6);
    const int lane = threadIdx.x & 63;
    float s = 0.f;
#pragma unroll
    for (int t = 0; t < 2; ++t) {
        int g = lane + t * 64;
        float cw1 = cls_w[g];
        if (g == 0) cw1 = -cw1;      // signs: only dim 0 negated
        s += x1[(size_t)r * DG_ + g] * cw1;
        s += x2f[(size_t)r * DG_ + g] * cls_w[DG_ + g];
    }
#pragma unroll
    for (int o = 32; o > 0; o >>= 1) s += __shfl_down(s, o, 64);
    if (lane == 0) dout[8 + r] = 2.0f + 2.0f * s + cls_b[0];
}

// ------------------------------------------------- top-k MIL (bitonic sort)
__global__ __launch_bounds__(256) void k_clas(
    const int* __restrict__ seq, float* __restrict__ dout)
{
    __shared__ float s[TT];
    const int b = blockIdx.x, tid = threadIdx.x;
    const int nb = seq[b];
    for (int t = tid; t < TT; t += 256)
        s[t] = (t < nb) ? dout[8 + b * TT + t] : -1e30f;
    __syncthreads();
    for (int k = 2; k <= TT; k <<= 1)
        for (int j = k >> 1; j > 0; j >>= 1) {
            for (int i = tid; i < TT; i += 256) {
                int ixj = i ^ j;
                if (ixj > i) {
                    float a = s[i], c = s[ixj];
                    bool descBlk = ((i & k) == 0);
                    if (descBlk ? (a < c) : (a > c)) { s[i] = c; s[ixj] = a; }
                }
            }
            __syncthreads();
        }
    const int kk = nb / 16 + 1;
    float part = 0.f;
    for (int t = tid; t < kk; t += 256) part += s[t];
#pragma unroll
    for (int o = 32; o > 0; o >>= 1) part += __shfl_down(part, o, 64);
    __shared__ float wred[4];
    if ((tid & 63) == 0) wred[tid >> 6] = part;
    __syncthreads();
    if (tid == 0) {
        float mil = (wred[0] + wred[1] + wred[2] + wred[3]) / (float)kk;
        dout[b] = 1.f / (1.f + expf(-mil));
    }
}

// ---------------------------------------------------------------- launch
extern "C" void kernel_launch(void* const* d_in, const int* in_sizes, int n_in,
                              void* d_out, int out_size, void* d_ws, size_t ws_size,
                              hipStream_t stream) {
    (void)in_sizes; (void)n_in; (void)out_size; (void)ws_size;
    const float* inputs = (const float*)d_in[0];
    const int*   seq    = (const int*)d_in[1];
    const float* w1     = (const float*)d_in[2];
    const float* b1     = (const float*)d_in[3];
    const float* w2     = (const float*)d_in[4];
    const float* b2     = (const float*)d_in[5];
    const float* gw1    = (const float*)d_in[6];
    const float* gw2    = (const float*)d_in[7];
    const float* cls_w  = (const float*)d_in[8];
    const float* cls_b  = (const float*)d_in[9];
    float* dout = (float*)d_out;
    float* ws = (float*)d_ws;

    float* px   = ws + o_px;
    float* C2   = ws + o_acc;                  // alias: C2 dead after k_proj
    float* accb = ws + o_acc;                  // zeroed after k_proj
    float* C1   = ws + o_A;
    unsigned short* pxb = (unsigned short*)(ws + o_A);  // alias: C1 dead after MLP2
    float* Y2   = ws + o_A;                    // alias: pxb dead after k_xy
    float* S    = ws + o_S;
    float* den  = ws + o_den;
    float* g1p  = ws + o_g1;
    float* g2p  = ws + o_g2;
    float* x1   = ws + o_px;                   // alias: px dead after k_band
    float* x2f  = ws + o_px + (size_t)MTOT * 128;

    // init
    k_zero<<<9, 256, 0, stream>>>(S, (size_t)BB * DHP);
    k_den_init<<<MTOT / 256, 256, 0, stream>>>(den, seq);
    k_padgw<<<(DHP * DG_ + 255) / 256, 256, 0, stream>>>(gw1, g1p);
    k_padgw<<<(DHP * DG_ + 255) / 256, 256, 0, stream>>>(gw2, g2p);

    // MLP (fp32, spill-fixed)
    gemm128_nt_leaky<<<dim3(D1_ / 128, MTOT / 128), 256, 0, stream>>>(
        inputs, 1152, w1, b1, C1, D1_, DV_);
    gemm128_nt_leaky<<<dim3(D2_ / 128, MTOT / 128), 256, 0, stream>>>(
        C1, D1_, w2, b2, C2, D2_, D1_);

    // expmap0: px fp32 + pxb bf16 (pxb overwrites C1)
    k_proj<<<MTOT, 256, 0, stream>>>(C2, inputs, px, pxb);

    // zero correction accumulator (kills C2 — already consumed)
    k_zero<<<4096, 256, 0, stream>>>(accb, NPX);

    // valid column sums
    k_ssum<<<dim3(BB, TT / 128), 256, 0, stream>>>(px, seq, S);

    // Lorentz similarity via bf16 MFMA, upper triangle
    k_xy_mfma<<<dim3(TT / 128, TT / 128, BB), 256, 0, stream>>>(pxb, px, seq, den, accb);

    // Y1 = (S + corr + diag)/den, zero for invalid rows
    k_y1<<<(int)(NPX / 256), 256, 0, stream>>>(accb, S, den, seq, px);

    // banded disadj @ px (Y2 overwrites pxb)
    k_band<<<dim3(TT / 8, BB), 256, 0, stream>>>(px, Y2);

    // graph-conv projections (x1/x2f overwrite px region)
    gemm_nn_leaky<<<dim3(DG_ / 64, MTOT / 64), 256, 0, stream>>>(accb, g1p, x1);
    gemm_nn_leaky<<<dim3(DG_ / 64, MTOT / 64), 256, 0, stream>>>(Y2, g2p, x2f);

    // frame_prob + MIL
    k_frame<<<MTOT / 4, 256, 0, stream>>>(x1, x2f, cls_w, cls_b, dout);
    k_clas<<<BB, 256, 0, stream>>>(seq, dout);
}

// Round 4
// 798.429 us; speedup vs baseline: 2.2562x; 1.7914x over previous
//
#include <hip/hip_runtime.h>
#include <math.h>

// ---------------------------------------------------------------- constants
#define BB 8
#define TT 2048
#define DV_ 1024
#define DA_ 128
#define D1_ 512
#define D2_ 128
#define DH_ 257
#define DHP 288            // padded (zeros): divisible by 32 for MFMA K-chunks
#define DG_ 128
#define MTOT (BB*TT)       // 16384 rows
#define NPX ((size_t)MTOT*DHP)

#define NEGS 0.01f
#define INV_E 0.36787944117144233f

// gap swizzle for B-tile LDS: insert 4-word gap every 32 words
#define SWZ(c) ((c) + ((((c) >> 5)) << 2))
#define BST 140            // 140%32=12 -> store groups land 2-way (free)
#define AST 132            // 132%32=4  -> 2-way stores; reads broadcast

// workspace layout (float offsets) — aliased to stay ~72 MB
static const size_t o_px  = 0;
static const size_t o_acc = NPX;                        // C2 -> accb -> Y1
static const size_t o_A   = 2*NPX;                      // C1 -> pxb -> Y2
static const size_t o_S   = o_A + (size_t)MTOT*D1_;
static const size_t o_den = o_S + BB*DHP;
static const size_t o_g1  = o_den + MTOT;
static const size_t o_g2  = o_g1 + DHP*DG_;

typedef __attribute__((ext_vector_type(8))) __bf16 bf16x8;
typedef __attribute__((ext_vector_type(4))) float f32x4;

__device__ __forceinline__ float diag_w() {
    // identical fp32 ops to the generic path evaluated at xy == 1.0f
    float dd = logf(1.0f + sqrtf(1.0f*1.0f - 1.0f + 1e-7f));
    dd = fminf(fmaxf(dd, 1e-6f), 200.0f);
    float x2 = expf(-dd);
    return expf(x2) - 1.0f;
}

__device__ __forceinline__ unsigned short f2bf(float f) {
    unsigned int u = __float_as_uint(f);
    u += 0x7FFFu + ((u >> 16) & 1u);   // RNE
    return (unsigned short)(u >> 16);
}

// ---------------------------------------------------------------- utilities
__global__ void k_zero(float* __restrict__ p, size_t n) {
    size_t i = (size_t)blockIdx.x * 256 + threadIdx.x;
    size_t stride = (size_t)gridDim.x * 256;
    for (; i < n; i += stride) p[i] = 0.f;
}

__global__ void k_den_init(float* __restrict__ den, const int* __restrict__ seq) {
    int r = blockIdx.x * 256 + threadIdx.x;   // 16384 total
    den[r] = (float)seq[r >> 11] + diag_w();
}

__global__ void k_padgw(const float* __restrict__ g, float* __restrict__ gp) {
    int i = blockIdx.x * 256 + threadIdx.x;   // DHP*DG total
    if (i < DHP * DG_) gp[i] = (i < DH_ * DG_) ? g[i] : 0.f;
}

// ------------------------------------------------- 128x128 fp32 GEMM core
#define STORE_A(v0, v1) \
    As[lk+0][lr]=v0.x; As[lk+1][lr]=v0.y; As[lk+2][lr]=v0.z; As[lk+3][lr]=v0.w; \
    As[lk+0][lr+64]=v1.x; As[lk+1][lr+64]=v1.y; As[lk+2][lr+64]=v1.z; As[lk+3][lr+64]=v1.w;
#define STORE_B(v0, v1) \
    Bs[lk+0][SWZ(lr)]=v0.x; Bs[lk+1][SWZ(lr)]=v0.y; Bs[lk+2][SWZ(lr)]=v0.z; Bs[lk+3][SWZ(lr)]=v0.w; \
    Bs[lk+0][SWZ(lr+64)]=v1.x; Bs[lk+1][SWZ(lr+64)]=v1.y; Bs[lk+2][SWZ(lr+64)]=v1.z; Bs[lk+3][SWZ(lr+64)]=v1.w;
#define INNER16(acc) \
    _Pragma("unroll") \
    for (int k = 0; k < 16; ++k) { \
        float4 aA = *(const float4*)&As[k][ty*8]; \
        float4 aB = *(const float4*)&As[k][ty*8+4]; \
        float4 bA = *(const float4*)&Bs[k][SWZ(tx*8)]; \
        float4 bB = *(const float4*)&Bs[k][SWZ(tx*8)+4]; \
        float ar[8] = {aA.x,aA.y,aA.z,aA.w,aB.x,aB.y,aB.z,aB.w}; \
        float br[8] = {bA.x,bA.y,bA.z,bA.w,bB.x,bB.y,bB.z,bB.w}; \
        _Pragma("unroll") \
        for (int ii = 0; ii < 8; ++ii) \
            _Pragma("unroll") \
            for (int jj = 0; jj < 8; ++jj) \
                acc[ii][jj] += ar[ii] * br[jj]; \
    }

// C = leaky(A*W^T + b); A [M x K] stride lda; W [N x K]
// __launch_bounds__(256, 1): max 256 threads, min 1 wave/EU -> VGPR budget 512.
// (r2: (256,4) clamped to 64 VGPR -> spill; r3: NO bounds ALSO defaults to a
//  64-VGPR occupancy target on gfx950 -> same spill. Must request low occupancy.)
__global__ __launch_bounds__(256, 1) void gemm128_nt_leaky(
    const float* __restrict__ A, int lda,
    const float* __restrict__ W, const float* __restrict__ bias,
    float* __restrict__ C, int N, int K)
{
    __shared__ float As[16][AST];
    __shared__ float Bs[16][BST];
    const int row0 = blockIdx.y * 128, col0 = blockIdx.x * 128;
    const int tid = threadIdx.x;
    const int lr = tid >> 2, lk = (tid & 3) * 4;
    const int tx = tid & 15, ty = tid >> 4;
    const float* Ar0 = A + (size_t)(row0 + lr) * lda + lk;
    const float* Ar1 = A + (size_t)(row0 + lr + 64) * lda + lk;
    const float* Wr0 = W + (size_t)(col0 + lr) * K + lk;
    const float* Wr1 = W + (size_t)(col0 + lr + 64) * K + lk;
    float4 a0 = *(const float4*)(Ar0);
    float4 a1 = *(const float4*)(Ar1);
    float4 w0 = *(const float4*)(Wr0);
    float4 w1 = *(const float4*)(Wr1);
    float acc[8][8] = {};
    for (int k0 = 16; ; k0 += 16) {
        __syncthreads();
        STORE_A(a0, a1)
        STORE_B(w0, w1)
        __syncthreads();
        bool more = (k0 < K);
        if (more) {
            a0 = *(const float4*)(Ar0 + k0);
            a1 = *(const float4*)(Ar1 + k0);
            w0 = *(const float4*)(Wr0 + k0);
            w1 = *(const float4*)(Wr1 + k0);
        }
        INNER16(acc)
        if (!more) break;
    }
#pragma unroll
    for (int ii = 0; ii < 8; ++ii) {
        int m = row0 + ty*8 + ii;
        float* crow = C + (size_t)m * N + col0 + tx*8;
#pragma unroll
        for (int jj = 0; jj < 8; ++jj) {
            float v = acc[ii][jj] + bias[col0 + tx*8 + jj];
            crow[jj] = (v >= 0.f) ? v : NEGS * v;
        }
    }
}

// ------------------------------------------------- xy via bf16 MFMA (upper tri)
__global__ __launch_bounds__(256) void k_xy_mfma(
    const unsigned short* __restrict__ pxb, const float* __restrict__ px,
    const int* __restrict__ seq, float* __restrict__ den, float* __restrict__ accb)
{
    const int b = blockIdx.z;
    const int bx = blockIdx.x, by = blockIdx.y;
    if (bx < by) return;
    const int nb = seq[b];
    const int row0 = by * 128, col0 = bx * 128;
    if (row0 >= nb || col0 >= nb) return;
    const int wave = threadIdx.x >> 6, lane = threadIdx.x & 63;
    const int r0 = row0 + (wave >> 1) * 64, c0 = col0 + (wave & 1) * 64;
    if (c0 + 63 < r0 || r0 >= nb || c0 >= nb) return;   // wave-uniform exits
    const unsigned short* base = pxb + (size_t)b * TT * DHP;
    const int q = lane >> 4, m = lane & 15;
    f32x4 acc[4][4];
#pragma unroll
    for (int a = 0; a < 4; ++a)
#pragma unroll
        for (int c = 0; c < 4; ++c) acc[a][c] = (f32x4){0.f, 0.f, 0.f, 0.f};
    for (int k0 = 0; k0 < DHP; k0 += 32) {
        bf16x8 af[4], bf[4];
#pragma unroll
        for (int t = 0; t < 4; ++t) {
            af[t] = *(const bf16x8*)(base + (size_t)(r0 + t*16 + m) * DHP + k0 + q*8);
            bf[t] = *(const bf16x8*)(base + (size_t)(c0 + t*16 + m) * DHP + k0 + q*8);
        }
#pragma unroll
        for (int mi = 0; mi < 4; ++mi)
#pragma unroll
            for (int nj = 0; nj < 4; ++nj)
                acc[mi][nj] = __builtin_amdgcn_mfma_f32_16x16x32_bf16(
                    af[mi], bf[nj], acc[mi][nj], 0, 0, 0);
    }
    const float* b32 = px + (size_t)b * TT * DHP;
    float cj[4], ci[4][4];
#pragma unroll
    for (int nj = 0; nj < 4; ++nj) cj[nj] = b32[(size_t)(c0 + nj*16 + m) * DHP];
#pragma unroll
    for (int mi = 0; mi < 4; ++mi)
#pragma unroll
        for (int t = 0; t < 4; ++t) ci[mi][t] = b32[(size_t)(r0 + mi*16 + q*4 + t) * DHP];
#pragma unroll
    for (int mi = 0; mi < 4; ++mi)
#pragma unroll
        for (int nj = 0; nj < 4; ++nj)
#pragma unroll
            for (int t = 0; t < 4; ++t) {
                int i = r0 + mi*16 + q*4 + t;
                int j = c0 + nj*16 + m;
                if (i < j && j < nb) {
                    float xyv = 2.f * ci[mi][t] * cj[nj] - acc[mi][nj][t];
                    float xym = fmaxf(xyv, 1.0f);
                    // xym >= 1.026 => x2 <= 0.798 < 0.8: no correction
                    if (xym < 1.026f) {
                        float dd = logf(xym + sqrtf(xym * xym - 1.0f + 1e-7f));
                        dd = fminf(fmaxf(dd, 1e-6f), 200.0f);
                        float x2v = expf(-dd);
                        if (x2v > 0.8f) {
                            float w = expf(x2v) - 1.0f;
                            atomicAdd(&den[b * TT + i], w);
                            atomicAdd(&den[b * TT + j], w);
                            const float* pi = b32 + (size_t)i * DHP;
                            const float* pj = b32 + (size_t)j * DHP;
                            float* ai = accb + ((size_t)(b * TT + i)) * DHP;
                            float* aj = accb + ((size_t)(b * TT + j)) * DHP;
                            for (int d = 0; d < DHP; ++d) {
                                atomicAdd(&ai[d], w * pj[d]);
                                atomicAdd(&aj[d], w * pi[d]);
                            }
                        }
                    }
                }
            }
}

// ------------------------------------------------- expmap0 (px fp32 + bf16)
__global__ __launch_bounds__(256) void k_proj(
    const float* __restrict__ C2, const float* __restrict__ inputs,
    float* __restrict__ px, unsigned short* __restrict__ pxb)
{
    const int r = blockIdx.x;
    const int tid = threadIdx.x;
    float v = (tid < 128) ? C2[(size_t)r * 128 + tid]
                          : inputs[(size_t)r * 1152 + 1024 + (tid - 128)];
    float sq = v * v;
#pragma unroll
    for (int o = 32; o > 0; o >>= 1) sq += __shfl_down(sq, o, 64);
    __shared__ float wred[4];
    __shared__ float cs[2];
    if ((tid & 63) == 0) wred[tid >> 6] = sq;
    __syncthreads();
    if (tid == 0) {
        float n2 = fmaxf(wred[0] + wred[1] + wred[2] + wred[3], 1e-12f);
        float n = sqrtf(n2);
        cs[0] = coshf(n);
        cs[1] = sinhf(n) / n;
    }
    __syncthreads();
    float sv = cs[1] * v;
    px[(size_t)r * DHP + 1 + tid] = sv;
    pxb[(size_t)r * DHP + 1 + tid] = f2bf(sv);
    if (tid == 0) {
        px[(size_t)r * DHP] = cs[0];
        pxb[(size_t)r * DHP] = f2bf(cs[0]);
    }
    if (tid < DHP - DH_) {   // 31 pad zeros
        px[(size_t)r * DHP + DH_ + tid] = 0.f;
        pxb[(size_t)r * DHP + DH_ + tid] = 0;
    }
}

// ------------------------------------------------- per-batch valid column sum
__global__ __launch_bounds__(256) void k_ssum(
    const float* __restrict__ px, const int* __restrict__ seq,
    float* __restrict__ S)
{
    const int b = blockIdx.x, chunk = blockIdx.y, tid = threadIdx.x;
    const int nb = seq[b];
    const int j0 = chunk * 128;
    const int j1 = (j0 + 128 < nb) ? j0 + 128 : nb;
    float a0 = 0.f, a1 = 0.f;
    const bool hasB = (tid < DHP - 256);
    for (int j = j0; j < j1; ++j) {
        const float* row = px + ((size_t)(b * TT + j)) * DHP;
        a0 += row[tid];
        if (hasB) a1 += row[256 + tid];
    }
    if (j1 > j0) {
        atomicAdd(&S[b * DHP + tid], a0);
        if (hasB) atomicAdd(&S[b * DHP + 256 + tid], a1);
    }
}

// ------------------------------------------------- Y1 = (S + corr + wd*px)/den
__global__ void k_y1(float* __restrict__ accb, const float* __restrict__ S,
                     const float* __restrict__ den, const int* __restrict__ seq,
                     const float* __restrict__ px)
{
    size_t idx = (size_t)blockIdx.x * 256 + threadIdx.x;
    if (idx >= NPX) return;
    int r = (int)(idx / DHP), d = (int)(idx % DHP);
    int b = r >> 11, i = r & (TT - 1);
    float out = 0.f;
    if (i < seq[b])
        out = (S[b * DHP + d] + accb[idx] + diag_w() * px[idx]) / den[r];
    accb[idx] = out;
}

// ------------------------------------------------- banded disadj @ px
__global__ __launch_bounds__(256) void k_band(
    const float* __restrict__ px, float* __restrict__ Y2)
{
    const int b = blockIdx.y;
    const int i0 = blockIdx.x * 8;
    const int tid = threadIdx.x;
    __shared__ float wtab[144];
    if (tid < 144) wtab[tid] = expf(-(float)tid * INV_E);
    __syncthreads();
    const int jlo = (i0 - 128 > 0) ? i0 - 128 : 0;
    const int jhi = (i0 + 7 + 128 < TT - 1) ? i0 + 7 + 128 : TT - 1;
    const float* base = px + (size_t)b * TT * DHP;
    const bool hasB = (tid < DHP - 256);
    float accA[8] = {}, accB[8] = {};
    for (int j = jlo; j <= jhi; ++j) {
        float pa = base[(size_t)j * DHP + tid];
        float pb = hasB ? base[(size_t)j * DHP + 256 + tid] : 0.f;
#pragma unroll
        for (int ii = 0; ii < 8; ++ii) {
            int dd = i0 + ii - j; dd = (dd < 0) ? -dd : dd;
            float w = wtab[dd];
            accA[ii] += w * pa;
            accB[ii] += w * pb;
        }
    }
#pragma unroll
    for (int ii = 0; ii < 8; ++ii) {
        Y2[((size_t)(b * TT + i0 + ii)) * DHP + tid] = accA[ii];
        if (hasB) Y2[((size_t)(b * TT + i0 + ii)) * DHP + 256 + tid] = accB[ii];
    }
}

// ------------------------------------------------- GEMM: C = leaky(A*G)  (NN)
__global__ __launch_bounds__(256) void gemm_nn_leaky(
    const float* __restrict__ A, const float* __restrict__ G,
    float* __restrict__ C)
{
    __shared__ float As[8][68];
    __shared__ float Gs[8][68];
    const int row0 = blockIdx.y * 64, col0 = blockIdx.x * 64;
    const int tid = threadIdx.x;
    const int tx = tid & 15, ty = tid >> 4;
    const int lr = tid >> 2, lc = (tid & 3) * 2;
    const int gk = tid >> 6, gc = tid & 63;
    float acc[4][4] = {};
    for (int k0 = 0; k0 < DHP; k0 += 8) {
        float2 av = *(const float2*)(A + (size_t)(row0 + lr) * DHP + k0 + lc);
        float g0 = G[(size_t)(k0 + gk) * DG_ + col0 + gc];
        float g1 = G[(size_t)(k0 + gk + 4) * DG_ + col0 + gc];
        __syncthreads();
        As[lc+0][lr] = av.x; As[lc+1][lr] = av.y;
        Gs[gk][gc] = g0; Gs[gk+4][gc] = g1;
        __syncthreads();
#pragma unroll
        for (int k = 0; k < 8; ++k) {
            float4 a = *(const float4*)&As[k][ty*4];
            float4 g = *(const float4*)&Gs[k][tx*4];
            acc[0][0]+=a.x*g.x; acc[0][1]+=a.x*g.y; acc[0][2]+=a.x*g.z; acc[0][3]+=a.x*g.w;
            acc[1][0]+=a.y*g.x; acc[1][1]+=a.y*g.y; acc[1][2]+=a.y*g.z; acc[1][3]+=a.y*g.w;
            acc[2][0]+=a.z*g.x; acc[2][1]+=a.z*g.y; acc[2][2]+=a.z*g.z; acc[2][3]+=a.z*g.w;
            acc[3][0]+=a.w*g.x; acc[3][1]+=a.w*g.y; acc[3][2]+=a.w*g.z; acc[3][3]+=a.w*g.w;
        }
    }
#pragma unroll
    for (int ii = 0; ii < 4; ++ii)
#pragma unroll
        for (int jj = 0; jj < 4; ++jj) {
            int m = row0 + ty*4 + ii, n = col0 + tx*4 + jj;
            float v = acc[ii][jj];
            C[(size_t)m * DG_ + n] = (v >= 0.f) ? v : NEGS * v;
        }
}

// ------------------------------------------------- frame_prob
__global__ __launch_bounds__(256) void k_frame(
    const float* __restrict__ x1, const float* __restrict__ x2f,
    const float* __restrict__ cls_w, const float* __restrict__ cls_b,
    float* __restrict__ dout)
{
    const int r = blockIdx.x * 4 + (threadIdx.x >> 6);
    const int lane = threadIdx.x & 63;
    float s = 0.f;
#pragma unroll
    for (int t = 0; t < 2; ++t) {
        int g = lane + t * 64;
        float cw1 = cls_w[g];
        if (g == 0) cw1 = -cw1;      // signs: only dim 0 negated
        s += x1[(size_t)r * DG_ + g] * cw1;
        s += x2f[(size_t)r * DG_ + g] * cls_w[DG_ + g];
    }
#pragma unroll
    for (int o = 32; o > 0; o >>= 1) s += __shfl_down(s, o, 64);
    if (lane == 0) dout[8 + r] = 2.0f + 2.0f * s + cls_b[0];
}

// ------------------------------------------------- top-k MIL (bitonic sort)
__global__ __launch_bounds__(256) void k_clas(
    const int* __restrict__ seq, float* __restrict__ dout)
{
    __shared__ float s[TT];
    const int b = blockIdx.x, tid = threadIdx.x;
    const int nb = seq[b];
    for (int t = tid; t < TT; t += 256)
        s[t] = (t < nb) ? dout[8 + b * TT + t] : -1e30f;
    __syncthreads();
    for (int k = 2; k <= TT; k <<= 1)
        for (int j = k >> 1; j > 0; j >>= 1) {
            for (int i = tid; i < TT; i += 256) {
                int ixj = i ^ j;
                if (ixj > i) {
                    float a = s[i], c = s[ixj];
                    bool descBlk = ((i & k) == 0);
                    if (descBlk ? (a < c) : (a > c)) { s[i] = c; s[ixj] = a; }
                }
            }
            __syncthreads();
        }
    const int kk = nb / 16 + 1;
    float part = 0.f;
    for (int t = tid; t < kk; t += 256) part += s[t];
#pragma unroll
    for (int o = 32; o > 0; o >>= 1) part += __shfl_down(part, o, 64);
    __shared__ float wred[4];
    if ((tid & 63) == 0) wred[tid >> 6] = part;
    __syncthreads();
    if (tid == 0) {
        float mil = (wred[0] + wred[1] + wred[2] + wred[3]) / (float)kk;
        dout[b] = 1.f / (1.f + expf(-mil));
    }
}

// ---------------------------------------------------------------- launch
extern "C" void kernel_launch(void* const* d_in, const int* in_sizes, int n_in,
                              void* d_out, int out_size, void* d_ws, size_t ws_size,
                              hipStream_t stream) {
    (void)in_sizes; (void)n_in; (void)out_size; (void)ws_size;
    const float* inputs = (const float*)d_in[0];
    const int*   seq    = (const int*)d_in[1];
    const float* w1     = (const float*)d_in[2];
    const float* b1     = (const float*)d_in[3];
    const float* w2     = (const float*)d_in[4];
    const float* b2     = (const float*)d_in[5];
    const float* gw1    = (const float*)d_in[6];
    const float* gw2    = (const float*)d_in[7];
    const float* cls_w  = (const float*)d_in[8];
    const float* cls_b  = (const float*)d_in[9];
    float* dout = (float*)d_out;
    float* ws = (float*)d_ws;

    float* px   = ws + o_px;
    float* C2   = ws + o_acc;                  // alias: C2 dead after k_proj
    float* accb = ws + o_acc;                  // zeroed after k_proj
    float* C1   = ws + o_A;
    unsigned short* pxb = (unsigned short*)(ws + o_A);  // alias: C1 dead after MLP2
    float* Y2   = ws + o_A;                    // alias: pxb dead after k_xy
    float* S    = ws + o_S;
    float* den  = ws + o_den;
    float* g1p  = ws + o_g1;
    float* g2p  = ws + o_g2;
    float* x1   = ws + o_px;                   // alias: px dead after k_band
    float* x2f  = ws + o_px + (size_t)MTOT * 128;

    // init
    k_zero<<<9, 256, 0, stream>>>(S, (size_t)BB * DHP);
    k_den_init<<<MTOT / 256, 256, 0, stream>>>(den, seq);
    k_padgw<<<(DHP * DG_ + 255) / 256, 256, 0, stream>>>(gw1, g1p);
    k_padgw<<<(DHP * DG_ + 255) / 256, 256, 0, stream>>>(gw2, g2p);

    // MLP (fp32)
    gemm128_nt_leaky<<<dim3(D1_ / 128, MTOT / 128), 256, 0, stream>>>(
        inputs, 1152, w1, b1, C1, D1_, DV_);
    gemm128_nt_leaky<<<dim3(D2_ / 128, MTOT / 128), 256, 0, stream>>>(
        C1, D1_, w2, b2, C2, D2_, D1_);

    // expmap0: px fp32 + pxb bf16 (pxb overwrites C1)
    k_proj<<<MTOT, 256, 0, stream>>>(C2, inputs, px, pxb);

    // zero correction accumulator (kills C2 — already consumed)
    k_zero<<<4096, 256, 0, stream>>>(accb, NPX);

    // valid column sums
    k_ssum<<<dim3(BB, TT / 128), 256, 0, stream>>>(px, seq, S);

    // Lorentz similarity via bf16 MFMA, upper triangle
    k_xy_mfma<<<dim3(TT / 128, TT / 128, BB), 256, 0, stream>>>(pxb, px, seq, den, accb);

    // Y1 = (S + corr + diag)/den, zero for invalid rows
    k_y1<<<(int)(NPX / 256), 256, 0, stream>>>(accb, S, den, seq, px);

    // banded disadj @ px (Y2 overwrites pxb)
    k_band<<<dim3(TT / 8, BB), 256, 0, stream>>>(px, Y2);

    // graph-conv projections (x1/x2f overwrite px region)
    gemm_nn_leaky<<<dim3(DG_ / 64, MTOT / 64), 256, 0, stream>>>(accb, g1p, x1);
    gemm_nn_leaky<<<dim3(DG_ / 64, MTOT / 64), 256, 0, stream>>>(Y2, g2p, x2f);

    // frame_prob + MIL
    k_frame<<<MTOT / 4, 256, 0, stream>>>(x1, x2f, cls_w, cls_b, dout);
    k_clas<<<BB, 256, 0, stream>>>(seq, dout);
}

// Round 5
// 734.014 us; speedup vs baseline: 2.4542x; 1.0878x over previous
//
#include <hip/hip_runtime.h>
#include <math.h>

// ---------------------------------------------------------------- constants
#define BB 8
#define TT 2048
#define DV_ 1024
#define DA_ 128
#define D1_ 512
#define D2_ 128
#define DH_ 257
#define DHP 288            // padded (zeros): divisible by 32 for MFMA K-chunks
#define DG_ 128
#define MTOT (BB*TT)       // 16384 rows
#define NPX ((size_t)MTOT*DHP)

#define NEGS 0.01f
#define INV_E 0.36787944117144233f

// ---------------------------------------------------------------- workspace
// float offsets; total ~27.9M floats (~112 MB)
//  o_big : Ah|Al bf16 [16384][1024] each  ->  px f32 | pxb | y2h/l | y1h/l
//  o_c1  : C1h|C1l bf16 [16384][512]      ->  accb f32 | x1 f32
//  o_c2  : C2 f32 [16384][128]            ->  x2f f32
static const size_t o_big = 0;                     // 16,777,216 f
static const size_t o_c1  = 16777216;              //  8,388,608 f
static const size_t o_c2  = o_c1 + 8388608;        //  2,097,152 f
static const size_t o_w   = o_c2 + 2097152;        //    663,552 f (split weights)
static const size_t o_S   = o_w + 663552;          //      2,304 f
static const size_t o_den = o_S + 2304;            //     16,384 f

// short offsets inside o_w
static const size_t sw_w1h = 0;          // 524,288
static const size_t sw_w1l = 524288;
static const size_t sw_w2h = 1048576;    // 65,536
static const size_t sw_w2l = 1114112;
static const size_t sw_g1h = 1179648;    // 36,864 ([128][288])
static const size_t sw_g1l = 1216512;
static const size_t sw_g2h = 1253376;
static const size_t sw_g2l = 1290240;

typedef __attribute__((ext_vector_type(8))) __bf16 bf16x8;
typedef __attribute__((ext_vector_type(4))) float f32x4;

__device__ __forceinline__ float diag_w() {
    // identical fp32 ops to the generic path evaluated at xy == 1.0f
    float dd = logf(1.0f + sqrtf(1.0f*1.0f - 1.0f + 1e-7f));
    dd = fminf(fmaxf(dd, 1e-6f), 200.0f);
    float x2 = expf(-dd);
    return expf(x2) - 1.0f;
}

__device__ __forceinline__ unsigned short f2bf(float f) {
    unsigned int u = __float_as_uint(f);
    u += 0x7FFFu + ((u >> 16) & 1u);   // RNE
    return (unsigned short)(u >> 16);
}
__device__ __forceinline__ float bf2f(unsigned short h) {
    return __uint_as_float((unsigned int)h << 16);
}

// ---------------------------------------------------------------- utilities
__global__ void k_zero(float* __restrict__ p, size_t n) {
    size_t i = (size_t)blockIdx.x * 256 + threadIdx.x;
    size_t stride = (size_t)gridDim.x * 256;
    for (; i < n; i += stride) p[i] = 0.f;
}

__global__ void k_den_init(float* __restrict__ den, const int* __restrict__ seq) {
    int r = blockIdx.x * 256 + threadIdx.x;   // 16384 total
    den[r] = (float)seq[r >> 11] + diag_w();
}

// contiguous fp32 -> (hi,lo) bf16 split, 4 elems/thread
__global__ void k_split_flat(const float* __restrict__ src,
                             unsigned short* __restrict__ h,
                             unsigned short* __restrict__ l, size_t n) {
    size_t i = ((size_t)blockIdx.x * 256 + threadIdx.x) * 4;
    if (i >= n) return;
    float4 v = *(const float4*)(src + i);
    ushort4 hv, lv;
    hv.x = f2bf(v.x); lv.x = f2bf(v.x - bf2f(hv.x));
    hv.y = f2bf(v.y); lv.y = f2bf(v.y - bf2f(hv.y));
    hv.z = f2bf(v.z); lv.z = f2bf(v.z - bf2f(hv.z));
    hv.w = f2bf(v.w); lv.w = f2bf(v.w - bf2f(hv.w));
    *(ushort4*)(h + i) = hv;
    *(ushort4*)(l + i) = lv;
}

// inputs[:, :, :1024] (row stride 1152) -> split [16384][1024]
__global__ void k_split_in(const float* __restrict__ inputs,
                           unsigned short* __restrict__ h,
                           unsigned short* __restrict__ l) {
    size_t i = ((size_t)blockIdx.x * 256 + threadIdx.x) * 4;
    if (i >= (size_t)MTOT * DV_) return;
    int r = (int)(i >> 10), c = (int)(i & 1023);
    float4 v = *(const float4*)(inputs + (size_t)r * 1152 + c);
    ushort4 hv, lv;
    hv.x = f2bf(v.x); lv.x = f2bf(v.x - bf2f(hv.x));
    hv.y = f2bf(v.y); lv.y = f2bf(v.y - bf2f(hv.y));
    hv.z = f2bf(v.z); lv.z = f2bf(v.z - bf2f(hv.z));
    hv.w = f2bf(v.w); lv.w = f2bf(v.w - bf2f(hv.w));
    *(ushort4*)(h + i) = hv;
    *(ushort4*)(l + i) = lv;
}

// gw [257][128] -> transposed, padded, split [128][288]
__global__ void k_padgw_t(const float* __restrict__ g,
                          unsigned short* __restrict__ th,
                          unsigned short* __restrict__ tl) {
    int i = blockIdx.x * 256 + threadIdx.x;   // DG*DHP = 36864
    if (i >= DG_ * DHP) return;
    int c = i / DHP, k = i - c * DHP;
    float v = (k < DH_) ? g[k * DG_ + c] : 0.f;
    unsigned short hh = f2bf(v);
    th[i] = hh;
    tl[i] = f2bf(v - bf2f(hh));
}

// ------------------------------------------------- split-bf16x3 MFMA GEMM (NT)
// C = leaky(A*B^T + bias). A,B given as (hi,lo) bf16 pairs; a*b ~ ah*bh+al*bh+ah*bl
// (error ~2^-17 rel ~ fp32). Block 128x128 = 4 waves of 64x64; direct global
// loads (L2-served). Outputs: Cf fp32 and/or (Ch,Cl) split — null to skip.
// (256,1): VGPR budget 512; needs ~150 (gfx950 defaults clamp to 64 -> spill).
__global__ __launch_bounds__(256, 1) void gemm_mfma_nt(
    const unsigned short* __restrict__ Ah, const unsigned short* __restrict__ Al, int lda,
    const unsigned short* __restrict__ Bh, const unsigned short* __restrict__ Bl, int ldb,
    const float* __restrict__ bias,
    float* __restrict__ Cf, unsigned short* __restrict__ Ch, unsigned short* __restrict__ Cl,
    int N, int K)
{
    const int row0 = blockIdx.y * 128, col0 = blockIdx.x * 128;
    const int wave = threadIdx.x >> 6, lane = threadIdx.x & 63;
    const int r0 = row0 + (wave >> 1) * 64, c0 = col0 + (wave & 1) * 64;
    const int q = lane >> 4, m = lane & 15;
    f32x4 acc[4][4];
#pragma unroll
    for (int a = 0; a < 4; ++a)
#pragma unroll
        for (int c = 0; c < 4; ++c) acc[a][c] = (f32x4){0.f, 0.f, 0.f, 0.f};
    for (int k0 = 0; k0 < K; k0 += 32) {
        bf16x8 ah[4], al[4], bh[4], bl[4];
#pragma unroll
        for (int t = 0; t < 4; ++t) {
            size_t ao = (size_t)(r0 + t*16 + m) * lda + k0 + q*8;
            size_t bo = (size_t)(c0 + t*16 + m) * ldb + k0 + q*8;
            ah[t] = *(const bf16x8*)(Ah + ao);
            al[t] = *(const bf16x8*)(Al + ao);
            bh[t] = *(const bf16x8*)(Bh + bo);
            bl[t] = *(const bf16x8*)(Bl + bo);
        }
#pragma unroll
        for (int mi = 0; mi < 4; ++mi)
#pragma unroll
            for (int nj = 0; nj < 4; ++nj) {
                acc[mi][nj] = __builtin_amdgcn_mfma_f32_16x16x32_bf16(
                    ah[mi], bh[nj], acc[mi][nj], 0, 0, 0);
                acc[mi][nj] = __builtin_amdgcn_mfma_f32_16x16x32_bf16(
                    al[mi], bh[nj], acc[mi][nj], 0, 0, 0);
                acc[mi][nj] = __builtin_amdgcn_mfma_f32_16x16x32_bf16(
                    ah[mi], bl[nj], acc[mi][nj], 0, 0, 0);
            }
    }
    float bj[4];
#pragma unroll
    for (int nj = 0; nj < 4; ++nj)
        bj[nj] = bias ? bias[c0 + nj*16 + m] : 0.f;
#pragma unroll
    for (int mi = 0; mi < 4; ++mi)
#pragma unroll
        for (int nj = 0; nj < 4; ++nj)
#pragma unroll
            for (int t = 0; t < 4; ++t) {
                int i = r0 + mi*16 + q*4 + t;
                int j = c0 + nj*16 + m;
                float v = acc[mi][nj][t] + bj[nj];
                v = (v >= 0.f) ? v : NEGS * v;
                size_t o = (size_t)i * N + j;
                if (Cf) Cf[o] = v;
                if (Ch) {
                    unsigned short hh = f2bf(v);
                    Ch[o] = hh;
                    Cl[o] = f2bf(v - bf2f(hh));
                }
            }
}

// ------------------------------------------------- xy via bf16 MFMA (upper tri)
// Only observable effect: which pairs pass x2>0.8. Off-diag xy ~1e13 vs band
// [1,1.026]; bf16 error ~1e11 -> classification identical to fp32/f64.
__global__ __launch_bounds__(256) void k_xy_mfma(
    const unsigned short* __restrict__ pxb, const float* __restrict__ px,
    const int* __restrict__ seq, float* __restrict__ den, float* __restrict__ accb)
{
    const int b = blockIdx.z;
    const int bx = blockIdx.x, by = blockIdx.y;
    if (bx < by) return;
    const int nb = seq[b];
    const int row0 = by * 128, col0 = bx * 128;
    if (row0 >= nb || col0 >= nb) return;
    const int wave = threadIdx.x >> 6, lane = threadIdx.x & 63;
    const int r0 = row0 + (wave >> 1) * 64, c0 = col0 + (wave & 1) * 64;
    if (c0 + 63 < r0 || r0 >= nb || c0 >= nb) return;   // wave-uniform exits
    const unsigned short* base = pxb + (size_t)b * TT * DHP;
    const int q = lane >> 4, m = lane & 15;
    f32x4 acc[4][4];
#pragma unroll
    for (int a = 0; a < 4; ++a)
#pragma unroll
        for (int c = 0; c < 4; ++c) acc[a][c] = (f32x4){0.f, 0.f, 0.f, 0.f};
    for (int k0 = 0; k0 < DHP; k0 += 32) {
        bf16x8 af[4], bf[4];
#pragma unroll
        for (int t = 0; t < 4; ++t) {
            af[t] = *(const bf16x8*)(base + (size_t)(r0 + t*16 + m) * DHP + k0 + q*8);
            bf[t] = *(const bf16x8*)(base + (size_t)(c0 + t*16 + m) * DHP + k0 + q*8);
        }
#pragma unroll
        for (int mi = 0; mi < 4; ++mi)
#pragma unroll
            for (int nj = 0; nj < 4; ++nj)
                acc[mi][nj] = __builtin_amdgcn_mfma_f32_16x16x32_bf16(
                    af[mi], bf[nj], acc[mi][nj], 0, 0, 0);
    }
    const float* b32 = px + (size_t)b * TT * DHP;
    float cj[4], ci[4][4];
#pragma unroll
    for (int nj = 0; nj < 4; ++nj) cj[nj] = b32[(size_t)(c0 + nj*16 + m) * DHP];
#pragma unroll
    for (int mi = 0; mi < 4; ++mi)
#pragma unroll
        for (int t = 0; t < 4; ++t) ci[mi][t] = b32[(size_t)(r0 + mi*16 + q*4 + t) * DHP];
#pragma unroll
    for (int mi = 0; mi < 4; ++mi)
#pragma unroll
        for (int nj = 0; nj < 4; ++nj)
#pragma unroll
            for (int t = 0; t < 4; ++t) {
                int i = r0 + mi*16 + q*4 + t;
                int j = c0 + nj*16 + m;
                if (i < j && j < nb) {
                    float xyv = 2.f * ci[mi][t] * cj[nj] - acc[mi][nj][t];
                    float xym = fmaxf(xyv, 1.0f);
                    // xym >= 1.026 => x2 <= 0.798 < 0.8: no correction
                    if (xym < 1.026f) {
                        float dd = logf(xym + sqrtf(xym * xym - 1.0f + 1e-7f));
                        dd = fminf(fmaxf(dd, 1e-6f), 200.0f);
                        float x2v = expf(-dd);
                        if (x2v > 0.8f) {
                            float w = expf(x2v) - 1.0f;
                            atomicAdd(&den[b * TT + i], w);
                            atomicAdd(&den[b * TT + j], w);
                            const float* pi = b32 + (size_t)i * DHP;
                            const float* pj = b32 + (size_t)j * DHP;
                            float* ai = accb + ((size_t)(b * TT + i)) * DHP;
                            float* aj = accb + ((size_t)(b * TT + j)) * DHP;
                            for (int d = 0; d < DHP; ++d) {
                                atomicAdd(&ai[d], w * pj[d]);
                                atomicAdd(&aj[d], w * pi[d]);
                            }
                        }
                    }
                }
            }
}

// ------------------------------------------------- expmap0 (px fp32 + bf16)
__global__ __launch_bounds__(256) void k_proj(
    const float* __restrict__ C2, const float* __restrict__ inputs,
    float* __restrict__ px, unsigned short* __restrict__ pxb)
{
    const int r = blockIdx.x;
    const int tid = threadIdx.x;
    float v = (tid < 128) ? C2[(size_t)r * 128 + tid]
                          : inputs[(size_t)r * 1152 + 1024 + (tid - 128)];
    float sq = v * v;
#pragma unroll
    for (int o = 32; o > 0; o >>= 1) sq += __shfl_down(sq, o, 64);
    __shared__ float wred[4];
    __shared__ float cs[2];
    if ((tid & 63) == 0) wred[tid >> 6] = sq;
    __syncthreads();
    if (tid == 0) {
        float n2 = fmaxf(wred[0] + wred[1] + wred[2] + wred[3], 1e-12f);
        float n = sqrtf(n2);
        cs[0] = coshf(n);
        cs[1] = sinhf(n) / n;
    }
    __syncthreads();
    float sv = cs[1] * v;
    px[(size_t)r * DHP + 1 + tid] = sv;
    pxb[(size_t)r * DHP + 1 + tid] = f2bf(sv);
    if (tid == 0) {
        px[(size_t)r * DHP] = cs[0];
        pxb[(size_t)r * DHP] = f2bf(cs[0]);
    }
    if (tid < DHP - DH_) {   // 31 pad zeros
        px[(size_t)r * DHP + DH_ + tid] = 0.f;
        pxb[(size_t)r * DHP + DH_ + tid] = 0;
    }
}

// ------------------------------------------------- per-batch valid column sum
__global__ __launch_bounds__(256) void k_ssum(
    const float* __restrict__ px, const int* __restrict__ seq,
    float* __restrict__ S)
{
    const int b = blockIdx.x, chunk = blockIdx.y, tid = threadIdx.x;
    const int nb = seq[b];
    const int j0 = chunk * 128;
    const int j1 = (j0 + 128 < nb) ? j0 + 128 : nb;
    float a0 = 0.f, a1 = 0.f;
    const bool hasB = (tid < DHP - 256);
    for (int j = j0; j < j1; ++j) {
        const float* row = px + ((size_t)(b * TT + j)) * DHP;
        a0 += row[tid];
        if (hasB) a1 += row[256 + tid];
    }
    if (j1 > j0) {
        atomicAdd(&S[b * DHP + tid], a0);
        if (hasB) atomicAdd(&S[b * DHP + 256 + tid], a1);
    }
}

// ------------------------------------------------- Y1 = (S + corr + wd*px)/den
// emits split bf16 for the downstream MFMA graph-conv
__global__ void k_y1(const float* __restrict__ accb, const float* __restrict__ S,
                     const float* __restrict__ den, const int* __restrict__ seq,
                     const float* __restrict__ px,
                     unsigned short* __restrict__ yh, unsigned short* __restrict__ yl)
{
    size_t idx = (size_t)blockIdx.x * 256 + threadIdx.x;
    if (idx >= NPX) return;
    int r = (int)(idx / DHP);
    int b = r >> 11, i = r & (TT - 1);
    int d = (int)(idx - (size_t)r * DHP);
    float out = 0.f;
    if (i < seq[b])
        out = (S[b * DHP + d] + accb[idx] + diag_w() * px[idx]) / den[r];
    unsigned short hh = f2bf(out);
    yh[idx] = hh;
    yl[idx] = f2bf(out - bf2f(hh));
}

// ------------------------------------------------- banded disadj @ px
// weight at |delta|=129 is 2e-21 -> truncate band at 128. Emits split bf16.
__global__ __launch_bounds__(256) void k_band(
    const float* __restrict__ px,
    unsigned short* __restrict__ yh, unsigned short* __restrict__ yl)
{
    const int b = blockIdx.y;
    const int i0 = blockIdx.x * 8;
    const int tid = threadIdx.x;
    __shared__ float wtab[144];
    if (tid < 144) wtab[tid] = expf(-(float)tid * INV_E);
    __syncthreads();
    const int jlo = (i0 - 128 > 0) ? i0 - 128 : 0;
    const int jhi = (i0 + 7 + 128 < TT - 1) ? i0 + 7 + 128 : TT - 1;
    const float* base = px + (size_t)b * TT * DHP;
    const bool hasB = (tid < DHP - 256);
    float accA[8] = {}, accB[8] = {};
    for (int j = jlo; j <= jhi; ++j) {
        float pa = base[(size_t)j * DHP + tid];
        float pb = hasB ? base[(size_t)j * DHP + 256 + tid] : 0.f;
#pragma unroll
        for (int ii = 0; ii < 8; ++ii) {
            int dd = i0 + ii - j; dd = (dd < 0) ? -dd : dd;
            float w = wtab[dd];
            accA[ii] += w * pa;
            accB[ii] += w * pb;
        }
    }
#pragma unroll
    for (int ii = 0; ii < 8; ++ii) {
        size_t oA = ((size_t)(b * TT + i0 + ii)) * DHP + tid;
        unsigned short hh = f2bf(accA[ii]);
        yh[oA] = hh; yl[oA] = f2bf(accA[ii] - bf2f(hh));
        if (hasB) {
            size_t oB = oA + 256 - tid + (256 + tid) - 256;  // = row*DHP + 256 + tid
            oB = ((size_t)(b * TT + i0 + ii)) * DHP + 256 + tid;
            unsigned short h2 = f2bf(accB[ii]);
            yh[oB] = h2; yl[oB] = f2bf(accB[ii] - bf2f(h2));
        }
    }
}

// ------------------------------------------------- frame_prob
__global__ __launch_bounds__(256) void k_frame(
    const float* __restrict__ x1, const float* __restrict__ x2f,
    const float* __restrict__ cls_w, const float* __restrict__ cls_b,
    float* __restrict__ dout)
{
    const int r = blockIdx.x * 4 + (threadIdx.x >> 6);
    const int lane = threadIdx.x & 63;
    float s = 0.f;
#pragma unroll
    for (int t = 0; t < 2; ++t) {
        int g = lane + t * 64;
        float cw1 = cls_w[g];
        if (g == 0) cw1 = -cw1;      // signs: only dim 0 negated
        s += x1[(size_t)r * DG_ + g] * cw1;
        s += x2f[(size_t)r * DG_ + g] * cls_w[DG_ + g];
    }
#pragma unroll
    for (int o = 32; o > 0; o >>= 1) s += __shfl_down(s, o, 64);
    if (lane == 0) dout[8 + r] = 2.0f + 2.0f * s + cls_b[0];
}

// ------------------------------------------------- top-k MIL (bitonic sort)
__global__ __launch_bounds__(256) void k_clas(
    const int* __restrict__ seq, float* __restrict__ dout)
{
    __shared__ float s[TT];
    const int b = blockIdx.x, tid = threadIdx.x;
    const int nb = seq[b];
    for (int t = tid; t < TT; t += 256)
        s[t] = (t < nb) ? dout[8 + b * TT + t] : -1e30f;
    __syncthreads();
    for (int k = 2; k <= TT; k <<= 1)
        for (int j = k >> 1; j > 0; j >>= 1) {
            for (int i = tid; i < TT; i += 256) {
                int ixj = i ^ j;
                if (ixj > i) {
                    float a = s[i], c = s[ixj];
                    bool descBlk = ((i & k) == 0);
                    if (descBlk ? (a < c) : (a > c)) { s[i] = c; s[ixj] = a; }
                }
            }
            __syncthreads();
        }
    const int kk = nb / 16 + 1;
    float part = 0.f;
    for (int t = tid; t < kk; t += 256) part += s[t];
#pragma unroll
    for (int o = 32; o > 0; o >>= 1) part += __shfl_down(part, o, 64);
    __shared__ float wred[4];
    if ((tid & 63) == 0) wred[tid >> 6] = part;
    __syncthreads();
    if (tid == 0) {
        float mil = (wred[0] + wred[1] + wred[2] + wred[3]) / (float)kk;
        dout[b] = 1.f / (1.f + expf(-mil));
    }
}

// ---------------------------------------------------------------- launch
extern "C" void kernel_launch(void* const* d_in, const int* in_sizes, int n_in,
                              void* d_out, int out_size, void* d_ws, size_t ws_size,
                              hipStream_t stream) {
    (void)in_sizes; (void)n_in; (void)out_size; (void)ws_size;
    const float* inputs = (const float*)d_in[0];
    const int*   seq    = (const int*)d_in[1];
    const float* w1     = (const float*)d_in[2];
    const float* b1     = (const float*)d_in[3];
    const float* w2     = (const float*)d_in[4];
    const float* b2     = (const float*)d_in[5];
    const float* gw1    = (const float*)d_in[6];
    const float* gw2    = (const float*)d_in[7];
    const float* cls_w  = (const float*)d_in[8];
    const float* cls_b  = (const float*)d_in[9];
    float* dout = (float*)d_out;
    float* ws = (float*)d_ws;

    // o_big region: Ah/Al -> px + pxb + y2 + y1
    unsigned short* Ah = (unsigned short*)(ws + o_big);
    unsigned short* Al = Ah + (size_t)MTOT * DV_;
    float* px  = ws + o_big;
    unsigned short* pxb = (unsigned short*)(ws + o_big + 4718592);
    unsigned short* y2h = (unsigned short*)(ws + o_big + 7077888);
    unsigned short* y2l = y2h + NPX;
    unsigned short* y1h = (unsigned short*)(ws + o_big + 11796480);
    unsigned short* y1l = y1h + NPX;
    // o_c1 region: C1h/C1l -> accb + x1
    unsigned short* C1h = (unsigned short*)(ws + o_c1);
    unsigned short* C1l = C1h + (size_t)MTOT * D1_;
    float* accb = ws + o_c1;
    float* x1   = ws + o_c1 + 4718592;
    // o_c2 region: C2 -> x2f
    float* C2  = ws + o_c2;
    float* x2f = ws + o_c2;
    // weights
    unsigned short* wsS = (unsigned short*)(ws + o_w);
    unsigned short *W1h = wsS + sw_w1h, *W1l = wsS + sw_w1l;
    unsigned short *W2h = wsS + sw_w2h, *W2l = wsS + sw_w2l;
    unsigned short *g1h = wsS + sw_g1h, *g1l = wsS + sw_g1l;
    unsigned short *g2h = wsS + sw_g2h, *g2l = wsS + sw_g2l;
    float* S   = ws + o_S;
    float* den = ws + o_den;

    // init + splits
    k_zero<<<9, 256, 0, stream>>>(S, (size_t)BB * DHP);
    k_den_init<<<MTOT / 256, 256, 0, stream>>>(den, seq);
    k_split_in<<<16384, 256, 0, stream>>>(inputs, Ah, Al);
    k_split_flat<<<512, 256, 0, stream>>>(w1, W1h, W1l, (size_t)D1_ * DV_);
    k_split_flat<<<64, 256, 0, stream>>>(w2, W2h, W2l, (size_t)D2_ * D1_);
    k_padgw_t<<<144, 256, 0, stream>>>(gw1, g1h, g1l);
    k_padgw_t<<<144, 256, 0, stream>>>(gw2, g2h, g2l);

    // MLP via split-bf16x3 MFMA
    gemm_mfma_nt<<<dim3(D1_ / 128, MTOT / 128), 256, 0, stream>>>(
        Ah, Al, DV_, W1h, W1l, DV_, b1, nullptr, C1h, C1l, D1_, DV_);
    gemm_mfma_nt<<<dim3(1, MTOT / 128), 256, 0, stream>>>(
        C1h, C1l, D1_, W2h, W2l, D1_, b2, C2, nullptr, nullptr, D2_, D1_);

    // expmap0 (px/pxb overwrite Ah region — Ah dead after MLP1)
    k_proj<<<MTOT, 256, 0, stream>>>(C2, inputs, px, pxb);

    // zero correction accumulator (overwrites C1 — dead after MLP2)
    k_zero<<<4096, 256, 0, stream>>>(accb, NPX);

    // valid column sums
    k_ssum<<<dim3(BB, TT / 128), 256, 0, stream>>>(px, seq, S);

    // Lorentz similarity via bf16 MFMA, upper triangle
    k_xy_mfma<<<dim3(TT / 128, TT / 128, BB), 256, 0, stream>>>(pxb, px, seq, den, accb);

    // Y1 = (S + corr + diag)/den -> split bf16
    k_y1<<<(int)(NPX / 256), 256, 0, stream>>>(accb, S, den, seq, px, y1h, y1l);

    // banded disadj @ px -> split bf16
    k_band<<<dim3(TT / 8, BB), 256, 0, stream>>>(px, y2h, y2l);

    // graph-conv projections via MFMA
    gemm_mfma_nt<<<dim3(1, MTOT / 128), 256, 0, stream>>>(
        y1h, y1l, DHP, g1h, g1l, DHP, nullptr, x1, nullptr, nullptr, DG_, DHP);
    gemm_mfma_nt<<<dim3(1, MTOT / 128), 256, 0, stream>>>(
        y2h, y2l, DHP, g2h, g2l, DHP, nullptr, x2f, nullptr, nullptr, DG_, DHP);

    // frame_prob + MIL
    k_frame<<<MTOT / 4, 256, 0, stream>>>(x1, x2f, cls_w, cls_b, dout);
    k_clas<<<BB, 256, 0, stream>>>(seq, dout);
}

// Round 6
// 683.738 us; speedup vs baseline: 2.6347x; 1.0735x over previous
//
#include <hip/hip_runtime.h>
#include <math.h>

// ---------------------------------------------------------------- constants
#define BB 8
#define TT 2048
#define DV_ 1024
#define DA_ 128
#define D1_ 512
#define D2_ 128
#define DH_ 257
#define DHP 288            // padded (zeros): divisible by 32 for MFMA K-chunks
#define DG_ 128
#define MTOT (BB*TT)       // 16384 rows
#define NPX ((size_t)MTOT*DHP)

#define NEGS 0.01f
#define INV_E 0.36787944117144233f
#define CH 64              // scan chunk rows
#define HALO 128           // r^128 ~ 3.5e-21: carry beyond halo is sub-eps

// ---------------------------------------------------------------- workspace
static const size_t o_big = 0;                     // 16,777,216 f
static const size_t o_c1  = 16777216;              //  8,388,608 f
static const size_t o_c2  = o_c1 + 8388608;        //  2,097,152 f
static const size_t o_w   = o_c2 + 2097152;        //    663,552 f (split weights)
static const size_t o_S   = o_w + 663552;          //      2,304 f
static const size_t o_den = o_S + 2304;            //     16,384 f

// short offsets inside o_w
static const size_t sw_w1h = 0;          // 524,288
static const size_t sw_w1l = 524288;
static const size_t sw_w2h = 1048576;    // 65,536
static const size_t sw_w2l = 1114112;
static const size_t sw_g1h = 1179648;    // 36,864 ([128][288])
static const size_t sw_g1l = 1216512;
static const size_t sw_g2h = 1253376;
static const size_t sw_g2l = 1290240;

typedef __attribute__((ext_vector_type(8))) __bf16 bf16x8;
typedef __attribute__((ext_vector_type(4))) float f32x4;

__device__ __forceinline__ float diag_w() {
    // identical fp32 ops to the generic path evaluated at xy == 1.0f
    float dd = logf(1.0f + sqrtf(1.0f*1.0f - 1.0f + 1e-7f));
    dd = fminf(fmaxf(dd, 1e-6f), 200.0f);
    float x2 = expf(-dd);
    return expf(x2) - 1.0f;
}

__device__ __forceinline__ unsigned short f2bf(float f) {
    unsigned int u = __float_as_uint(f);
    u += 0x7FFFu + ((u >> 16) & 1u);   // RNE
    return (unsigned short)(u >> 16);
}
__device__ __forceinline__ float bf2f(unsigned short h) {
    return __uint_as_float((unsigned int)h << 16);
}

// ---------------------------------------------------------------- utilities
__global__ void k_zero(float* __restrict__ p, size_t n) {
    size_t i = (size_t)blockIdx.x * 256 + threadIdx.x;
    size_t stride = (size_t)gridDim.x * 256;
    for (; i < n; i += stride) p[i] = 0.f;
}

__global__ void k_den_init(float* __restrict__ den, const int* __restrict__ seq) {
    int r = blockIdx.x * 256 + threadIdx.x;   // 16384 total
    den[r] = (float)seq[r >> 11] + diag_w();
}

// contiguous fp32 -> (hi,lo) bf16 split, 4 elems/thread
__global__ void k_split_flat(const float* __restrict__ src,
                             unsigned short* __restrict__ h,
                             unsigned short* __restrict__ l, size_t n) {
    size_t i = ((size_t)blockIdx.x * 256 + threadIdx.x) * 4;
    if (i >= n) return;
    float4 v = *(const float4*)(src + i);
    ushort4 hv, lv;
    hv.x = f2bf(v.x); lv.x = f2bf(v.x - bf2f(hv.x));
    hv.y = f2bf(v.y); lv.y = f2bf(v.y - bf2f(hv.y));
    hv.z = f2bf(v.z); lv.z = f2bf(v.z - bf2f(hv.z));
    hv.w = f2bf(v.w); lv.w = f2bf(v.w - bf2f(hv.w));
    *(ushort4*)(h + i) = hv;
    *(ushort4*)(l + i) = lv;
}

// inputs[:, :, :1024] (row stride 1152) -> split [16384][1024]
__global__ void k_split_in(const float* __restrict__ inputs,
                           unsigned short* __restrict__ h,
                           unsigned short* __restrict__ l) {
    size_t i = ((size_t)blockIdx.x * 256 + threadIdx.x) * 4;
    if (i >= (size_t)MTOT * DV_) return;
    int r = (int)(i >> 10), c = (int)(i & 1023);
    float4 v = *(const float4*)(inputs + (size_t)r * 1152 + c);
    ushort4 hv, lv;
    hv.x = f2bf(v.x); lv.x = f2bf(v.x - bf2f(hv.x));
    hv.y = f2bf(v.y); lv.y = f2bf(v.y - bf2f(hv.y));
    hv.z = f2bf(v.z); lv.z = f2bf(v.z - bf2f(hv.z));
    hv.w = f2bf(v.w); lv.w = f2bf(v.w - bf2f(hv.w));
    *(ushort4*)(h + i) = hv;
    *(ushort4*)(l + i) = lv;
}

// gw [257][128] -> transposed, padded, split [128][288]
__global__ void k_padgw_t(const float* __restrict__ g,
                          unsigned short* __restrict__ th,
                          unsigned short* __restrict__ tl) {
    int i = blockIdx.x * 256 + threadIdx.x;   // DG*DHP = 36864
    if (i >= DG_ * DHP) return;
    int c = i / DHP, k = i - c * DHP;
    float v = (k < DH_) ? g[k * DG_ + c] : 0.f;
    unsigned short hh = f2bf(v);
    th[i] = hh;
    tl[i] = f2bf(v - bf2f(hh));
}

// ------------------------------------------------- split-bf16x3 MFMA GEMM (NT)
// C = leaky(A*B^T + bias). a*b ~ ah*bh+al*bh+ah*bl (error ~2^-17 rel ~ fp32).
// (256,1): VGPR budget 512 (gfx950 defaults clamp to 64 -> spill).
__global__ __launch_bounds__(256, 1) void gemm_mfma_nt(
    const unsigned short* __restrict__ Ah, const unsigned short* __restrict__ Al, int lda,
    const unsigned short* __restrict__ Bh, const unsigned short* __restrict__ Bl, int ldb,
    const float* __restrict__ bias,
    float* __restrict__ Cf, unsigned short* __restrict__ Ch, unsigned short* __restrict__ Cl,
    int N, int K)
{
    const int row0 = blockIdx.y * 128, col0 = blockIdx.x * 128;
    const int wave = threadIdx.x >> 6, lane = threadIdx.x & 63;
    const int r0 = row0 + (wave >> 1) * 64, c0 = col0 + (wave & 1) * 64;
    const int q = lane >> 4, m = lane & 15;
    f32x4 acc[4][4];
#pragma unroll
    for (int a = 0; a < 4; ++a)
#pragma unroll
        for (int c = 0; c < 4; ++c) acc[a][c] = (f32x4){0.f, 0.f, 0.f, 0.f};
    for (int k0 = 0; k0 < K; k0 += 32) {
        bf16x8 ah[4], al[4], bh[4], bl[4];
#pragma unroll
        for (int t = 0; t < 4; ++t) {
            size_t ao = (size_t)(r0 + t*16 + m) * lda + k0 + q*8;
            size_t bo = (size_t)(c0 + t*16 + m) * ldb + k0 + q*8;
            ah[t] = *(const bf16x8*)(Ah + ao);
            al[t] = *(const bf16x8*)(Al + ao);
            bh[t] = *(const bf16x8*)(Bh + bo);
            bl[t] = *(const bf16x8*)(Bl + bo);
        }
#pragma unroll
        for (int mi = 0; mi < 4; ++mi)
#pragma unroll
            for (int nj = 0; nj < 4; ++nj) {
                acc[mi][nj] = __builtin_amdgcn_mfma_f32_16x16x32_bf16(
                    ah[mi], bh[nj], acc[mi][nj], 0, 0, 0);
                acc[mi][nj] = __builtin_amdgcn_mfma_f32_16x16x32_bf16(
                    al[mi], bh[nj], acc[mi][nj], 0, 0, 0);
                acc[mi][nj] = __builtin_amdgcn_mfma_f32_16x16x32_bf16(
                    ah[mi], bl[nj], acc[mi][nj], 0, 0, 0);
            }
    }
    float bj[4];
#pragma unroll
    for (int nj = 0; nj < 4; ++nj)
        bj[nj] = bias ? bias[c0 + nj*16 + m] : 0.f;
#pragma unroll
    for (int mi = 0; mi < 4; ++mi)
#pragma unroll
        for (int nj = 0; nj < 4; ++nj)
#pragma unroll
            for (int t = 0; t < 4; ++t) {
                int i = r0 + mi*16 + q*4 + t;
                int j = c0 + nj*16 + m;
                float v = acc[mi][nj][t] + bj[nj];
                v = (v >= 0.f) ? v : NEGS * v;
                size_t o = (size_t)i * N + j;
                if (Cf) Cf[o] = v;
                if (Ch) {
                    unsigned short hh = f2bf(v);
                    Ch[o] = hh;
                    Cl[o] = f2bf(v - bf2f(hh));
                }
            }
}

// ------------------------------------------------- xy via bf16 MFMA (upper tri)
// Only observable effect: which pairs pass x2>0.8. Off-diag xy ~1e13 vs band
// [1,1.026]; bf16 error ~1e11 -> classification identical to fp32/f64.
__global__ __launch_bounds__(256) void k_xy_mfma(
    const unsigned short* __restrict__ pxb, const float* __restrict__ px,
    const int* __restrict__ seq, float* __restrict__ den, float* __restrict__ accb)
{
    const int b = blockIdx.z;
    const int bx = blockIdx.x, by = blockIdx.y;
    if (bx < by) return;
    const int nb = seq[b];
    const int row0 = by * 128, col0 = bx * 128;
    if (row0 >= nb || col0 >= nb) return;
    const int wave = threadIdx.x >> 6, lane = threadIdx.x & 63;
    const int r0 = row0 + (wave >> 1) * 64, c0 = col0 + (wave & 1) * 64;
    if (c0 + 63 < r0 || r0 >= nb || c0 >= nb) return;   // wave-uniform exits
    const unsigned short* base = pxb + (size_t)b * TT * DHP;
    const int q = lane >> 4, m = lane & 15;
    f32x4 acc[4][4];
#pragma unroll
    for (int a = 0; a < 4; ++a)
#pragma unroll
        for (int c = 0; c < 4; ++c) acc[a][c] = (f32x4){0.f, 0.f, 0.f, 0.f};
    for (int k0 = 0; k0 < DHP; k0 += 32) {
        bf16x8 af[4], bf[4];
#pragma unroll
        for (int t = 0; t < 4; ++t) {
            af[t] = *(const bf16x8*)(base + (size_t)(r0 + t*16 + m) * DHP + k0 + q*8);
            bf[t] = *(const bf16x8*)(base + (size_t)(c0 + t*16 + m) * DHP + k0 + q*8);
        }
#pragma unroll
        for (int mi = 0; mi < 4; ++mi)
#pragma unroll
            for (int nj = 0; nj < 4; ++nj)
                acc[mi][nj] = __builtin_amdgcn_mfma_f32_16x16x32_bf16(
                    af[mi], bf[nj], acc[mi][nj], 0, 0, 0);
    }
    const float* b32 = px + (size_t)b * TT * DHP;
    float cj[4], ci[4][4];
#pragma unroll
    for (int nj = 0; nj < 4; ++nj) cj[nj] = b32[(size_t)(c0 + nj*16 + m) * DHP];
#pragma unroll
    for (int mi = 0; mi < 4; ++mi)
#pragma unroll
        for (int t = 0; t < 4; ++t) ci[mi][t] = b32[(size_t)(r0 + mi*16 + q*4 + t) * DHP];
#pragma unroll
    for (int mi = 0; mi < 4; ++mi)
#pragma unroll
        for (int nj = 0; nj < 4; ++nj)
#pragma unroll
            for (int t = 0; t < 4; ++t) {
                int i = r0 + mi*16 + q*4 + t;
                int j = c0 + nj*16 + m;
                if (i < j && j < nb) {
                    float xyv = 2.f * ci[mi][t] * cj[nj] - acc[mi][nj][t];
                    float xym = fmaxf(xyv, 1.0f);
                    // xym >= 1.026 => x2 <= 0.798 < 0.8: no correction
                    if (xym < 1.026f) {
                        float dd = logf(xym + sqrtf(xym * xym - 1.0f + 1e-7f));
                        dd = fminf(fmaxf(dd, 1e-6f), 200.0f);
                        float x2v = expf(-dd);
                        if (x2v > 0.8f) {
                            float w = expf(x2v) - 1.0f;
                            atomicAdd(&den[b * TT + i], w);
                            atomicAdd(&den[b * TT + j], w);
                            const float* pi = b32 + (size_t)i * DHP;
                            const float* pj = b32 + (size_t)j * DHP;
                            float* ai = accb + ((size_t)(b * TT + i)) * DHP;
                            float* aj = accb + ((size_t)(b * TT + j)) * DHP;
                            for (int d = 0; d < DHP; ++d) {
                                atomicAdd(&ai[d], w * pj[d]);
                                atomicAdd(&aj[d], w * pi[d]);
                            }
                        }
                    }
                }
            }
}

// ------------------------------------------------- expmap0 (px fp32 + bf16)
__global__ __launch_bounds__(256) void k_proj(
    const float* __restrict__ C2, const float* __restrict__ inputs,
    float* __restrict__ px, unsigned short* __restrict__ pxb)
{
    const int r = blockIdx.x;
    const int tid = threadIdx.x;
    float v = (tid < 128) ? C2[(size_t)r * 128 + tid]
                          : inputs[(size_t)r * 1152 + 1024 + (tid - 128)];
    float sq = v * v;
#pragma unroll
    for (int o = 32; o > 0; o >>= 1) sq += __shfl_down(sq, o, 64);
    __shared__ float wred[4];
    __shared__ float cs[2];
    if ((tid & 63) == 0) wred[tid >> 6] = sq;
    __syncthreads();
    if (tid == 0) {
        float n2 = fmaxf(wred[0] + wred[1] + wred[2] + wred[3], 1e-12f);
        float n = sqrtf(n2);
        cs[0] = coshf(n);
        cs[1] = sinhf(n) / n;
    }
    __syncthreads();
    float sv = cs[1] * v;
    px[(size_t)r * DHP + 1 + tid] = sv;
    pxb[(size_t)r * DHP + 1 + tid] = f2bf(sv);
    if (tid == 0) {
        px[(size_t)r * DHP] = cs[0];
        pxb[(size_t)r * DHP] = f2bf(cs[0]);
    }
    if (tid < DHP - DH_) {   // 31 pad zeros
        px[(size_t)r * DHP + DH_ + tid] = 0.f;
        pxb[(size_t)r * DHP + DH_ + tid] = 0;
    }
}

// ------------------------------------------------- per-batch valid column sum
__global__ __launch_bounds__(256) void k_ssum(
    const float* __restrict__ px, const int* __restrict__ seq,
    float* __restrict__ S)
{
    const int b = blockIdx.x, chunk = blockIdx.y, tid = threadIdx.x;
    const int nb = seq[b];
    const int j0 = chunk * 128;
    const int j1 = (j0 + 128 < nb) ? j0 + 128 : nb;
    float a0 = 0.f, a1 = 0.f;
    const bool hasB = (tid < DHP - 256);
    for (int j = j0; j < j1; ++j) {
        const float* row = px + ((size_t)(b * TT + j)) * DHP;
        a0 += row[tid];
        if (hasB) a1 += row[256 + tid];
    }
    if (j1 > j0) {
        atomicAdd(&S[b * DHP + tid], a0);
        if (hasB) atomicAdd(&S[b * DHP + 256 + tid], a1);
    }
}

// ------------------------------------------------- Y1 = (S + corr + wd*px)/den
// emits split bf16 for the downstream MFMA graph-conv
__global__ void k_y1(const float* __restrict__ accb, const float* __restrict__ S,
                     const float* __restrict__ den, const int* __restrict__ seq,
                     const float* __restrict__ px,
                     unsigned short* __restrict__ yh, unsigned short* __restrict__ yl)
{
    size_t idx = (size_t)blockIdx.x * 256 + threadIdx.x;
    if (idx >= NPX) return;
    int r = (int)(idx / DHP);
    int b = r >> 11, i = r & (TT - 1);
    int d = (int)(idx - (size_t)r * DHP);
    float out = 0.f;
    if (i < seq[b])
        out = (S[b * DHP + d] + accb[idx] + diag_w() * px[idx]) / den[r];
    unsigned short hh = f2bf(out);
    yh[idx] = hh;
    yl[idx] = f2bf(out - bf2f(hh));
}

// ------------------------------------------------- disadj @ px via dual scan
// disadj[i,j] = r^|i-j|, r = exp(-1/e). Full matvec = fwd + bwd recursion:
//   F_i = px_i + r F_{i-1};  G_i = px_i + r G_{i+1};  y_i = F_i + G_i - px_i.
// Chunk of CH=64 rows with HALO=128 warmup (carry decay r^128 ~ 3.5e-21:
// sub-fp32-eps on any px scale). 6 row-reads + 2 FMA per output vs 33/33
// for the windowed version (r5: 177 us, FETCH 284 MB).
__global__ __launch_bounds__(256) void k_band(
    const float* __restrict__ px,
    unsigned short* __restrict__ yh, unsigned short* __restrict__ yl)
{
    __shared__ float Fs[CH][DHP];   // 73,728 B
    const int b = blockIdx.y;
    const int i0 = blockIdx.x * CH;
    const int tid = threadIdx.x;
    const bool hasB = (tid < DHP - 256);
    const float r = expf(-INV_E);
    const float* base = px + (size_t)b * TT * DHP;

    // forward scan with left halo
    {
        const int jlo = (i0 - HALO > 0) ? i0 - HALO : 0;
        float LA = 0.f, LB = 0.f;
        for (int j = jlo; j < i0 + CH; ++j) {
            const float* row = base + (size_t)j * DHP;
            LA = fmaf(r, LA, row[tid]);
            if (hasB) LB = fmaf(r, LB, row[256 + tid]);
            if (j >= i0) {
                Fs[j - i0][tid] = LA;
                if (hasB) Fs[j - i0][256 + tid] = LB;
            }
        }
    }
    __syncthreads();
    // backward scan with right halo; emit y = F + G - px
    {
        const int jhi = (i0 + CH - 1 + HALO < TT - 1) ? i0 + CH - 1 + HALO : TT - 1;
        float RA = 0.f, RB = 0.f;
        for (int j = jhi; j >= i0; --j) {
            const float* row = base + (size_t)j * DHP;
            float pa = row[tid];
            float pb = hasB ? row[256 + tid] : 0.f;
            RA = fmaf(r, RA, pa);
            if (hasB) RB = fmaf(r, RB, pb);
            if (j < i0 + CH) {
                size_t o = ((size_t)(b * TT + j)) * DHP + tid;
                float ya = Fs[j - i0][tid] + RA - pa;
                unsigned short hh = f2bf(ya);
                yh[o] = hh; yl[o] = f2bf(ya - bf2f(hh));
                if (hasB) {
                    float yb = Fs[j - i0][256 + tid] + RB - pb;
                    size_t ob = o + 256;
                    unsigned short h2 = f2bf(yb);
                    yh[ob] = h2; yl[ob] = f2bf(yb - bf2f(h2));
                }
            }
        }
    }
}

// ------------------------------------------------- frame_prob
__global__ __launch_bounds__(256) void k_frame(
    const float* __restrict__ x1, const float* __restrict__ x2f,
    const float* __restrict__ cls_w, const float* __restrict__ cls_b,
    float* __restrict__ dout)
{
    const int r = blockIdx.x * 4 + (threadIdx.x >> 6);
    const int lane = threadIdx.x & 63;
    float s = 0.f;
#pragma unroll
    for (int t = 0; t < 2; ++t) {
        int g = lane + t * 64;
        float cw1 = cls_w[g];
        if (g == 0) cw1 = -cw1;      // signs: only dim 0 negated
        s += x1[(size_t)r * DG_ + g] * cw1;
        s += x2f[(size_t)r * DG_ + g] * cls_w[DG_ + g];
    }
#pragma unroll
    for (int o = 32; o > 0; o >>= 1) s += __shfl_down(s, o, 64);
    if (lane == 0) dout[8 + r] = 2.0f + 2.0f * s + cls_b[0];
}

// ------------------------------------------------- top-k MIL (bitonic sort)
__global__ __launch_bounds__(256) void k_clas(
    const int* __restrict__ seq, float* __restrict__ dout)
{
    __shared__ float s[TT];
    const int b = blockIdx.x, tid = threadIdx.x;
    const int nb = seq[b];
    for (int t = tid; t < TT; t += 256)
        s[t] = (t < nb) ? dout[8 + b * TT + t] : -1e30f;
    __syncthreads();
    for (int k = 2; k <= TT; k <<= 1)
        for (int j = k >> 1; j > 0; j >>= 1) {
            for (int i = tid; i < TT; i += 256) {
                int ixj = i ^ j;
                if (ixj > i) {
                    float a = s[i], c = s[ixj];
                    bool descBlk = ((i & k) == 0);
                    if (descBlk ? (a < c) : (a > c)) { s[i] = c; s[ixj] = a; }
                }
            }
            __syncthreads();
        }
    const int kk = nb / 16 + 1;
    float part = 0.f;
    for (int t = tid; t < kk; t += 256) part += s[t];
#pragma unroll
    for (int o = 32; o > 0; o >>= 1) part += __shfl_down(part, o, 64);
    __shared__ float wred[4];
    if ((tid & 63) == 0) wred[tid >> 6] = part;
    __syncthreads();
    if (tid == 0) {
        float mil = (wred[0] + wred[1] + wred[2] + wred[3]) / (float)kk;
        dout[b] = 1.f / (1.f + expf(-mil));
    }
}

// ---------------------------------------------------------------- launch
extern "C" void kernel_launch(void* const* d_in, const int* in_sizes, int n_in,
                              void* d_out, int out_size, void* d_ws, size_t ws_size,
                              hipStream_t stream) {
    (void)in_sizes; (void)n_in; (void)out_size; (void)ws_size;
    const float* inputs = (const float*)d_in[0];
    const int*   seq    = (const int*)d_in[1];
    const float* w1     = (const float*)d_in[2];
    const float* b1     = (const float*)d_in[3];
    const float* w2     = (const float*)d_in[4];
    const float* b2     = (const float*)d_in[5];
    const float* gw1    = (const float*)d_in[6];
    const float* gw2    = (const float*)d_in[7];
    const float* cls_w  = (const float*)d_in[8];
    const float* cls_b  = (const float*)d_in[9];
    float* dout = (float*)d_out;
    float* ws = (float*)d_ws;

    // o_big region: Ah/Al -> px + pxb + y2 + y1
    unsigned short* Ah = (unsigned short*)(ws + o_big);
    unsigned short* Al = Ah + (size_t)MTOT * DV_;
    float* px  = ws + o_big;
    unsigned short* pxb = (unsigned short*)(ws + o_big + 4718592);
    unsigned short* y2h = (unsigned short*)(ws + o_big + 7077888);
    unsigned short* y2l = y2h + NPX;
    unsigned short* y1h = (unsigned short*)(ws + o_big + 11796480);
    unsigned short* y1l = y1h + NPX;
    // o_c1 region: C1h/C1l -> accb + x1
    unsigned short* C1h = (unsigned short*)(ws + o_c1);
    unsigned short* C1l = C1h + (size_t)MTOT * D1_;
    float* accb = ws + o_c1;
    float* x1   = ws + o_c1 + 4718592;
    // o_c2 region: C2 -> x2f
    float* C2  = ws + o_c2;
    float* x2f = ws + o_c2;
    // weights
    unsigned short* wsS = (unsigned short*)(ws + o_w);
    unsigned short *W1h = wsS + sw_w1h, *W1l = wsS + sw_w1l;
    unsigned short *W2h = wsS + sw_w2h, *W2l = wsS + sw_w2l;
    unsigned short *g1h = wsS + sw_g1h, *g1l = wsS + sw_g1l;
    unsigned short *g2h = wsS + sw_g2h, *g2l = wsS + sw_g2l;
    float* S   = ws + o_S;
    float* den = ws + o_den;

    // init + splits
    k_zero<<<9, 256, 0, stream>>>(S, (size_t)BB * DHP);
    k_den_init<<<MTOT / 256, 256, 0, stream>>>(den, seq);
    k_split_in<<<16384, 256, 0, stream>>>(inputs, Ah, Al);
    k_split_flat<<<512, 256, 0, stream>>>(w1, W1h, W1l, (size_t)D1_ * DV_);
    k_split_flat<<<64, 256, 0, stream>>>(w2, W2h, W2l, (size_t)D2_ * D1_);
    k_padgw_t<<<144, 256, 0, stream>>>(gw1, g1h, g1l);
    k_padgw_t<<<144, 256, 0, stream>>>(gw2, g2h, g2l);

    // MLP via split-bf16x3 MFMA
    gemm_mfma_nt<<<dim3(D1_ / 128, MTOT / 128), 256, 0, stream>>>(
        Ah, Al, DV_, W1h, W1l, DV_, b1, nullptr, C1h, C1l, D1_, DV_);
    gemm_mfma_nt<<<dim3(1, MTOT / 128), 256, 0, stream>>>(
        C1h, C1l, D1_, W2h, W2l, D1_, b2, C2, nullptr, nullptr, D2_, D1_);

    // expmap0 (px/pxb overwrite Ah region — Ah dead after MLP1)
    k_proj<<<MTOT, 256, 0, stream>>>(C2, inputs, px, pxb);

    // zero correction accumulator (overwrites C1 — dead after MLP2)
    k_zero<<<4096, 256, 0, stream>>>(accb, NPX);

    // valid column sums
    k_ssum<<<dim3(BB, TT / 128), 256, 0, stream>>>(px, seq, S);

    // Lorentz similarity via bf16 MFMA, upper triangle
    k_xy_mfma<<<dim3(TT / 128, TT / 128, BB), 256, 0, stream>>>(pxb, px, seq, den, accb);

    // Y1 = (S + corr + diag)/den -> split bf16
    k_y1<<<(int)(NPX / 256), 256, 0, stream>>>(accb, S, den, seq, px, y1h, y1l);

    // disadj @ px via dual scan -> split bf16
    k_band<<<dim3(TT / CH, BB), 256, 0, stream>>>(px, y2h, y2l);

    // graph-conv projections via MFMA
    gemm_mfma_nt<<<dim3(1, MTOT / 128), 256, 0, stream>>>(
        y1h, y1l, DHP, g1h, g1l, DHP, nullptr, x1, nullptr, nullptr, DG_, DHP);
    gemm_mfma_nt<<<dim3(1, MTOT / 128), 256, 0, stream>>>(
        y2h, y2l, DHP, g2h, g2l, DHP, nullptr, x2f, nullptr, nullptr, DG_, DHP);

    // frame_prob + MIL
    k_frame<<<MTOT / 4, 256, 0, stream>>>(x1, x2f, cls_w, cls_b, dout);
    k_clas<<<BB, 256, 0, stream>>>(seq, dout);
}

// Round 7
// 598.686 us; speedup vs baseline: 3.0090x; 1.1421x over previous
//
#include <hip/hip_runtime.h>
#include <math.h>

// ---------------------------------------------------------------- constants
#define BB 8
#define TT 2048
#define DV_ 1024
#define DA_ 128
#define D1_ 512
#define D2_ 128
#define DH_ 257
#define DHP 288            // padded (zeros): divisible by 32 for MFMA K-chunks
#define DG_ 128
#define MTOT (BB*TT)       // 16384 rows
#define NPX ((size_t)MTOT*DHP)

#define NEGS 0.01f
#define INV_E 0.36787944117144233f
#define CH 64              // scan chunk rows
#define HALO 128           // r^128 ~ 3.5e-21: carry beyond halo is sub-eps

// ---------------------------------------------------------------- workspace
static const size_t o_big = 0;                     // 16,777,216 f
static const size_t o_c1  = 16777216;              //  8,388,608 f
static const size_t o_c2  = o_c1 + 8388608;        //  2,097,152 f
static const size_t o_w   = o_c2 + 2097152;        //    663,552 f (split weights)
static const size_t o_S   = o_w + 663552;          //      2,304 f
static const size_t o_den = o_S + 2304;            //     16,384 f

// short offsets inside o_w
static const size_t sw_w1h = 0;          // 524,288
static const size_t sw_w1l = 524288;
static const size_t sw_w2h = 1048576;    // 65,536
static const size_t sw_w2l = 1114112;
static const size_t sw_g1h = 1179648;    // 36,864 ([128][288])
static const size_t sw_g1l = 1216512;
static const size_t sw_g2h = 1253376;
static const size_t sw_g2l = 1290240;

typedef __attribute__((ext_vector_type(8))) __bf16 bf16x8;
typedef __attribute__((ext_vector_type(4))) float f32x4;

__device__ __forceinline__ float diag_w() {
    // identical fp32 ops to the generic path evaluated at xy == 1.0f
    float dd = logf(1.0f + sqrtf(1.0f*1.0f - 1.0f + 1e-7f));
    dd = fminf(fmaxf(dd, 1e-6f), 200.0f);
    float x2 = expf(-dd);
    return expf(x2) - 1.0f;
}

__device__ __forceinline__ unsigned short f2bf(float f) {
    unsigned int u = __float_as_uint(f);
    u += 0x7FFFu + ((u >> 16) & 1u);   // RNE
    return (unsigned short)(u >> 16);
}
__device__ __forceinline__ float bf2f(unsigned short h) {
    return __uint_as_float((unsigned int)h << 16);
}

// ---------------------------------------------------------------- utilities
__global__ void k_zero(float* __restrict__ p, size_t n) {
    size_t i = (size_t)blockIdx.x * 256 + threadIdx.x;
    size_t stride = (size_t)gridDim.x * 256;
    for (; i < n; i += stride) p[i] = 0.f;
}

// den init + S zero (merged)
__global__ void k_init(float* __restrict__ den, const int* __restrict__ seq,
                       float* __restrict__ S) {
    int r = blockIdx.x * 256 + threadIdx.x;   // 16384 total
    den[r] = (float)seq[r >> 11] + diag_w();
    if (r < BB * DHP) S[r] = 0.f;
}

// w1 + w2 fp32 -> (hi,lo) bf16 split in one launch
__global__ void k_split_w(const float* __restrict__ w1, const float* __restrict__ w2,
                          unsigned short* __restrict__ h1, unsigned short* __restrict__ l1,
                          unsigned short* __restrict__ h2, unsigned short* __restrict__ l2) {
    size_t i = ((size_t)blockIdx.x * 256 + threadIdx.x) * 4;
    const float* src; unsigned short *h, *l; size_t o;
    if (i < (size_t)D1_ * DV_) { src = w1; h = h1; l = l1; o = i; }
    else {
        o = i - (size_t)D1_ * DV_;
        if (o >= (size_t)D2_ * D1_) return;
        src = w2; h = h2; l = l2;
    }
    float4 v = *(const float4*)(src + o);
    ushort4 hv, lv;
    hv.x = f2bf(v.x); lv.x = f2bf(v.x - bf2f(hv.x));
    hv.y = f2bf(v.y); lv.y = f2bf(v.y - bf2f(hv.y));
    hv.z = f2bf(v.z); lv.z = f2bf(v.z - bf2f(hv.z));
    hv.w = f2bf(v.w); lv.w = f2bf(v.w - bf2f(hv.w));
    *(ushort4*)(h + o) = hv;
    *(ushort4*)(l + o) = lv;
}

// inputs[:, :, :1024] (row stride 1152) -> split [16384][1024]
__global__ void k_split_in(const float* __restrict__ inputs,
                           unsigned short* __restrict__ h,
                           unsigned short* __restrict__ l) {
    size_t i = ((size_t)blockIdx.x * 256 + threadIdx.x) * 4;
    if (i >= (size_t)MTOT * DV_) return;
    int r = (int)(i >> 10), c = (int)(i & 1023);
    float4 v = *(const float4*)(inputs + (size_t)r * 1152 + c);
    ushort4 hv, lv;
    hv.x = f2bf(v.x); lv.x = f2bf(v.x - bf2f(hv.x));
    hv.y = f2bf(v.y); lv.y = f2bf(v.y - bf2f(hv.y));
    hv.z = f2bf(v.z); lv.z = f2bf(v.z - bf2f(hv.z));
    hv.w = f2bf(v.w); lv.w = f2bf(v.w - bf2f(hv.w));
    *(ushort4*)(h + i) = hv;
    *(ushort4*)(l + i) = lv;
}

// gw1/gw2 [257][128] -> transposed, padded, split [128][288]; blockIdx.y picks
__global__ void k_padgw_t(const float* __restrict__ g1, const float* __restrict__ g2,
                          unsigned short* __restrict__ h1, unsigned short* __restrict__ l1,
                          unsigned short* __restrict__ h2, unsigned short* __restrict__ l2) {
    int i = blockIdx.x * 256 + threadIdx.x;   // DG*DHP = 36864
    if (i >= DG_ * DHP) return;
    const float* g = blockIdx.y ? g2 : g1;
    unsigned short* th = blockIdx.y ? h2 : h1;
    unsigned short* tl = blockIdx.y ? l2 : l1;
    int c = i / DHP, k = i - c * DHP;
    float v = (k < DH_) ? g[k * DG_ + c] : 0.f;
    unsigned short hh = f2bf(v);
    th[i] = hh;
    tl[i] = f2bf(v - bf2f(hh));
}

// ------------------------------------------------- split-bf16x3 MFMA GEMM (NT)
// C = leaky(A*B^T + bias). a*b ~ ah*bh+al*bh+ah*bl (error ~2^-17 rel ~ fp32).
// Register double-buffer prefetch: next K-chunk's 16 loads issue before the
// current 48-MFMA burst (~230 cyc) so L2 latency (~200-400) is hidden.
// (256,1): VGPR budget 512; needs ~220 (gfx950 defaults clamp to 64 -> spill).
#define LOADK(S, k0) \
    _Pragma("unroll") \
    for (int t = 0; t < 4; ++t) { \
        size_t ao = (size_t)(r0 + t*16 + m) * lda + (k0) + q*8; \
        size_t bo = (size_t)(c0 + t*16 + m) * ldb + (k0) + q*8; \
        ah##S[t] = *(const bf16x8*)(Ah + ao); \
        al##S[t] = *(const bf16x8*)(Al + ao); \
        bh##S[t] = *(const bf16x8*)(Bh + bo); \
        bl##S[t] = *(const bf16x8*)(Bl + bo); \
    }
#define MFMAK(S) \
    _Pragma("unroll") \
    for (int mi = 0; mi < 4; ++mi) \
        _Pragma("unroll") \
        for (int nj = 0; nj < 4; ++nj) { \
            acc[mi][nj] = __builtin_amdgcn_mfma_f32_16x16x32_bf16(ah##S[mi], bh##S[nj], acc[mi][nj], 0, 0, 0); \
            acc[mi][nj] = __builtin_amdgcn_mfma_f32_16x16x32_bf16(al##S[mi], bh##S[nj], acc[mi][nj], 0, 0, 0); \
            acc[mi][nj] = __builtin_amdgcn_mfma_f32_16x16x32_bf16(ah##S[mi], bl##S[nj], acc[mi][nj], 0, 0, 0); \
        }

__global__ __launch_bounds__(256, 1) void gemm_mfma_nt(
    const unsigned short* __restrict__ Ah, const unsigned short* __restrict__ Al, int lda,
    const unsigned short* __restrict__ Bh, const unsigned short* __restrict__ Bl, int ldb,
    const float* __restrict__ bias,
    float* __restrict__ Cf, unsigned short* __restrict__ Ch, unsigned short* __restrict__ Cl,
    int N, int K)
{
    const int row0 = blockIdx.y * 128, col0 = blockIdx.x * 128;
    const int wave = threadIdx.x >> 6, lane = threadIdx.x & 63;
    const int r0 = row0 + (wave >> 1) * 64, c0 = col0 + (wave & 1) * 64;
    const int q = lane >> 4, m = lane & 15;
    f32x4 acc[4][4];
#pragma unroll
    for (int a = 0; a < 4; ++a)
#pragma unroll
        for (int c = 0; c < 4; ++c) acc[a][c] = (f32x4){0.f, 0.f, 0.f, 0.f};
    bf16x8 ah0[4], al0[4], bh0[4], bl0[4];
    bf16x8 ah1[4], al1[4], bh1[4], bl1[4];
    LOADK(0, 0)
    int k0 = 0;
    for (; k0 + 64 <= K; k0 += 64) {
        LOADK(1, k0 + 32)
        MFMAK(0)
        if (k0 + 64 < K) { LOADK(0, k0 + 64) }
        MFMAK(1)
    }
    if (k0 < K) { MFMAK(0) }   // odd tail chunk (K=288)
    float bj[4];
#pragma unroll
    for (int nj = 0; nj < 4; ++nj)
        bj[nj] = bias ? bias[c0 + nj*16 + m] : 0.f;
#pragma unroll
    for (int mi = 0; mi < 4; ++mi)
#pragma unroll
        for (int nj = 0; nj < 4; ++nj)
#pragma unroll
            for (int t = 0; t < 4; ++t) {
                int i = r0 + mi*16 + q*4 + t;
                int j = c0 + nj*16 + m;
                float v = acc[mi][nj][t] + bj[nj];
                v = (v >= 0.f) ? v : NEGS * v;
                size_t o = (size_t)i * N + j;
                if (Cf) Cf[o] = v;
                if (Ch) {
                    unsigned short hh = f2bf(v);
                    Ch[o] = hh;
                    Cl[o] = f2bf(v - bf2f(hh));
                }
            }
}

// ------------------------------------------------- xy via bf16 MFMA (upper tri)
// Only observable effect: which pairs pass x2>0.8. Off-diag xy ~1e13 vs band
// [1,1.026]; bf16 error ~1e11 -> classification identical to fp32/f64.
// (256,1): acc+frags need ~150 VGPR — default bounds clamp to 64 -> acc spill
// (r3-r6 latent bug, same failure mode as r2's gemm128).
#define XLOAD(S, k0) \
    _Pragma("unroll") \
    for (int t = 0; t < 4; ++t) { \
        af##S[t] = *(const bf16x8*)(base + (size_t)(r0 + t*16 + m) * DHP + (k0) + q*8); \
        bf##S[t] = *(const bf16x8*)(base + (size_t)(c0 + t*16 + m) * DHP + (k0) + q*8); \
    }
#define XMFMA(S) \
    _Pragma("unroll") \
    for (int mi = 0; mi < 4; ++mi) \
        _Pragma("unroll") \
        for (int nj = 0; nj < 4; ++nj) \
            acc[mi][nj] = __builtin_amdgcn_mfma_f32_16x16x32_bf16(af##S[mi], bf##S[nj], acc[mi][nj], 0, 0, 0);

__global__ __launch_bounds__(256, 1) void k_xy_mfma(
    const unsigned short* __restrict__ pxb, const float* __restrict__ px,
    const int* __restrict__ seq, float* __restrict__ den, float* __restrict__ accb)
{
    const int b = blockIdx.z;
    const int bx = blockIdx.x, by = blockIdx.y;
    if (bx < by) return;
    const int nb = seq[b];
    const int row0 = by * 128, col0 = bx * 128;
    if (row0 >= nb || col0 >= nb) return;
    const int wave = threadIdx.x >> 6, lane = threadIdx.x & 63;
    const int r0 = row0 + (wave >> 1) * 64, c0 = col0 + (wave & 1) * 64;
    if (c0 + 63 < r0 || r0 >= nb || c0 >= nb) return;   // wave-uniform exits
    const unsigned short* base = pxb + (size_t)b * TT * DHP;
    const int q = lane >> 4, m = lane & 15;
    f32x4 acc[4][4];
#pragma unroll
    for (int a = 0; a < 4; ++a)
#pragma unroll
        for (int c = 0; c < 4; ++c) acc[a][c] = (f32x4){0.f, 0.f, 0.f, 0.f};
    bf16x8 af0[4], bf0[4], af1[4], bf1[4];
    XLOAD(0, 0)
    int k0 = 0;
    for (; k0 + 64 <= DHP; k0 += 64) {
        XLOAD(1, k0 + 32)
        XMFMA(0)
        if (k0 + 64 < DHP) { XLOAD(0, k0 + 64) }
        XMFMA(1)
    }
    if (k0 < DHP) { XMFMA(0) }
    const float* b32 = px + (size_t)b * TT * DHP;
    float cj[4], ci[4][4];
#pragma unroll
    for (int nj = 0; nj < 4; ++nj) cj[nj] = b32[(size_t)(c0 + nj*16 + m) * DHP];
#pragma unroll
    for (int mi = 0; mi < 4; ++mi)
#pragma unroll
        for (int t = 0; t < 4; ++t) ci[mi][t] = b32[(size_t)(r0 + mi*16 + q*4 + t) * DHP];
#pragma unroll
    for (int mi = 0; mi < 4; ++mi)
#pragma unroll
        for (int nj = 0; nj < 4; ++nj)
#pragma unroll
            for (int t = 0; t < 4; ++t) {
                int i = r0 + mi*16 + q*4 + t;
                int j = c0 + nj*16 + m;
                if (i < j && j < nb) {
                    float xyv = 2.f * ci[mi][t] * cj[nj] - acc[mi][nj][t];
                    float xym = fmaxf(xyv, 1.0f);
                    // xym >= 1.026 => x2 <= 0.798 < 0.8: no correction
                    if (xym < 1.026f) {
                        float dd = logf(xym + sqrtf(xym * xym - 1.0f + 1e-7f));
                        dd = fminf(fmaxf(dd, 1e-6f), 200.0f);
                        float x2v = expf(-dd);
                        if (x2v > 0.8f) {
                            float w = expf(x2v) - 1.0f;
                            atomicAdd(&den[b * TT + i], w);
                            atomicAdd(&den[b * TT + j], w);
                            const float* pi = b32 + (size_t)i * DHP;
                            const float* pj = b32 + (size_t)j * DHP;
                            float* ai = accb + ((size_t)(b * TT + i)) * DHP;
                            float* aj = accb + ((size_t)(b * TT + j)) * DHP;
                            for (int d = 0; d < DHP; ++d) {
                                atomicAdd(&ai[d], w * pj[d]);
                                atomicAdd(&aj[d], w * pi[d]);
                            }
                        }
                    }
                }
            }
}

// ------------------------------------------------- expmap0 (px fp32 + bf16)
__global__ __launch_bounds__(256) void k_proj(
    const float* __restrict__ C2, const float* __restrict__ inputs,
    float* __restrict__ px, unsigned short* __restrict__ pxb)
{
    const int r = blockIdx.x;
    const int tid = threadIdx.x;
    float v = (tid < 128) ? C2[(size_t)r * 128 + tid]
                          : inputs[(size_t)r * 1152 + 1024 + (tid - 128)];
    float sq = v * v;
#pragma unroll
    for (int o = 32; o > 0; o >>= 1) sq += __shfl_down(sq, o, 64);
    __shared__ float wred[4];
    __shared__ float cs[2];
    if ((tid & 63) == 0) wred[tid >> 6] = sq;
    __syncthreads();
    if (tid == 0) {
        float n2 = fmaxf(wred[0] + wred[1] + wred[2] + wred[3], 1e-12f);
        float n = sqrtf(n2);
        cs[0] = coshf(n);
        cs[1] = sinhf(n) / n;
    }
    __syncthreads();
    float sv = cs[1] * v;
    px[(size_t)r * DHP + 1 + tid] = sv;
    pxb[(size_t)r * DHP + 1 + tid] = f2bf(sv);
    if (tid == 0) {
        px[(size_t)r * DHP] = cs[0];
        pxb[(size_t)r * DHP] = f2bf(cs[0]);
    }
    if (tid < DHP - DH_) {   // 31 pad zeros
        px[(size_t)r * DHP + DH_ + tid] = 0.f;
        pxb[(size_t)r * DHP + DH_ + tid] = 0;
    }
}

// ------------------------------------------------- per-batch valid column sum
__global__ __launch_bounds__(256) void k_ssum(
    const float* __restrict__ px, const int* __restrict__ seq,
    float* __restrict__ S)
{
    const int b = blockIdx.x, chunk = blockIdx.y, tid = threadIdx.x;
    const int nb = seq[b];
    const int j0 = chunk * 32;
    const int j1 = (j0 + 32 < nb) ? j0 + 32 : nb;
    float a0 = 0.f, a1 = 0.f;
    const bool hasB = (tid < DHP - 256);
    for (int j = j0; j < j1; ++j) {
        const float* row = px + ((size_t)(b * TT + j)) * DHP;
        a0 += row[tid];
        if (hasB) a1 += row[256 + tid];
    }
    if (j1 > j0) {
        atomicAdd(&S[b * DHP + tid], a0);
        if (hasB) atomicAdd(&S[b * DHP + 256 + tid], a1);
    }
}

// ------------------------------------------------- Y1 = (S + corr + wd*px)/den
// emits split bf16 for the downstream MFMA graph-conv
__global__ void k_y1(const float* __restrict__ accb, const float* __restrict__ S,
                     const float* __restrict__ den, const int* __restrict__ seq,
                     const float* __restrict__ px,
                     unsigned short* __restrict__ yh, unsigned short* __restrict__ yl)
{
    size_t idx = (size_t)blockIdx.x * 256 + threadIdx.x;
    if (idx >= NPX) return;
    int r = (int)(idx / DHP);
    int b = r >> 11, i = r & (TT - 1);
    int d = (int)(idx - (size_t)r * DHP);
    float out = 0.f;
    if (i < seq[b])
        out = (S[b * DHP + d] + accb[idx] + diag_w() * px[idx]) / den[r];
    unsigned short hh = f2bf(out);
    yh[idx] = hh;
    yl[idx] = f2bf(out - bf2f(hh));
}

// ------------------------------------------------- disadj @ px via dual scan
// disadj[i,j] = r^|i-j|: full matvec = fwd + bwd first-order recursions with
// HALO=128 warmup (carry decay r^128 ~ 3.5e-21 — sub-fp32-eps at any px scale).
__global__ __launch_bounds__(256) void k_band(
    const float* __restrict__ px,
    unsigned short* __restrict__ yh, unsigned short* __restrict__ yl)
{
    __shared__ float Fs[CH][DHP];   // 73,728 B
    const int b = blockIdx.y;
    const int i0 = blockIdx.x * CH;
    const int tid = threadIdx.x;
    const bool hasB = (tid < DHP - 256);
    const float r = expf(-INV_E);
    const float* base = px + (size_t)b * TT * DHP;

    // forward scan with left halo
    {
        const int jlo = (i0 - HALO > 0) ? i0 - HALO : 0;
        float LA = 0.f, LB = 0.f;
        for (int j = jlo; j < i0 + CH; ++j) {
            const float* row = base + (size_t)j * DHP;
            LA = fmaf(r, LA, row[tid]);
            if (hasB) LB = fmaf(r, LB, row[256 + tid]);
            if (j >= i0) {
                Fs[j - i0][tid] = LA;
                if (hasB) Fs[j - i0][256 + tid] = LB;
            }
        }
    }
    __syncthreads();
    // backward scan with right halo; emit y = F + G - px
    {
        const int jhi = (i0 + CH - 1 + HALO < TT - 1) ? i0 + CH - 1 + HALO : TT - 1;
        float RA = 0.f, RB = 0.f;
        for (int j = jhi; j >= i0; --j) {
            const float* row = base + (size_t)j * DHP;
            float pa = row[tid];
            float pb = hasB ? row[256 + tid] : 0.f;
            RA = fmaf(r, RA, pa);
            if (hasB) RB = fmaf(r, RB, pb);
            if (j < i0 + CH) {
                size_t o = ((size_t)(b * TT + j)) * DHP + tid;
                float ya = Fs[j - i0][tid] + RA - pa;
                unsigned short hh = f2bf(ya);
                yh[o] = hh; yl[o] = f2bf(ya - bf2f(hh));
                if (hasB) {
                    float yb = Fs[j - i0][256 + tid] + RB - pb;
                    size_t ob = o + 256;
                    unsigned short h2 = f2bf(yb);
                    yh[ob] = h2; yl[ob] = f2bf(yb - bf2f(h2));
                }
            }
        }
    }
}

// ------------------------------------------------- frame_prob
__global__ __launch_bounds__(256) void k_frame(
    const float* __restrict__ x1, const float* __restrict__ x2f,
    const float* __restrict__ cls_w, const float* __restrict__ cls_b,
    float* __restrict__ dout)
{
    const int r = blockIdx.x * 4 + (threadIdx.x >> 6);
    const int lane = threadIdx.x & 63;
    float s = 0.f;
#pragma unroll
    for (int t = 0; t < 2; ++t) {
        int g = lane + t * 64;
        float cw1 = cls_w[g];
        if (g == 0) cw1 = -cw1;      // signs: only dim 0 negated
        s += x1[(size_t)r * DG_ + g] * cw1;
        s += x2f[(size_t)r * DG_ + g] * cls_w[DG_ + g];
    }
#pragma unroll
    for (int o = 32; o > 0; o >>= 1) s += __shfl_down(s, o, 64);
    if (lane == 0) dout[8 + r] = 2.0f + 2.0f * s + cls_b[0];
}

// ------------------------------------------------- top-k MIL (bitonic sort)
__global__ __launch_bounds__(1024) void k_clas(
    const int* __restrict__ seq, float* __restrict__ dout)
{
    __shared__ float s[TT];
    const int b = blockIdx.x, tid = threadIdx.x;
    const int nb = seq[b];
    for (int t = tid; t < TT; t += 1024)
        s[t] = (t < nb) ? dout[8 + b * TT + t] : -1e30f;
    __syncthreads();
    for (int k = 2; k <= TT; k <<= 1)
        for (int j = k >> 1; j > 0; j >>= 1) {
            for (int i = tid; i < TT; i += 1024) {
                int ixj = i ^ j;
                if (ixj > i) {
                    float a = s[i], c = s[ixj];
                    bool descBlk = ((i & k) == 0);
                    if (descBlk ? (a < c) : (a > c)) { s[i] = c; s[ixj] = a; }
                }
            }
            __syncthreads();
        }
    const int kk = nb / 16 + 1;
    float part = 0.f;
    for (int t = tid; t < kk; t += 1024) part += s[t];
#pragma unroll
    for (int o = 32; o > 0; o >>= 1) part += __shfl_down(part, o, 64);
    __shared__ float wred[16];
    if ((tid & 63) == 0) wred[tid >> 6] = part;
    __syncthreads();
    if (tid == 0) {
        float mil = 0.f;
#pragma unroll
        for (int t = 0; t < 16; ++t) mil += wred[t];
        mil /= (float)kk;
        dout[b] = 1.f / (1.f + expf(-mil));
    }
}

// ---------------------------------------------------------------- launch
extern "C" void kernel_launch(void* const* d_in, const int* in_sizes, int n_in,
                              void* d_out, int out_size, void* d_ws, size_t ws_size,
                              hipStream_t stream) {
    (void)in_sizes; (void)n_in; (void)out_size; (void)ws_size;
    const float* inputs = (const float*)d_in[0];
    const int*   seq    = (const int*)d_in[1];
    const float* w1     = (const float*)d_in[2];
    const float* b1     = (const float*)d_in[3];
    const float* w2     = (const float*)d_in[4];
    const float* b2     = (const float*)d_in[5];
    const float* gw1    = (const float*)d_in[6];
    const float* gw2    = (const float*)d_in[7];
    const float* cls_w  = (const float*)d_in[8];
    const float* cls_b  = (const float*)d_in[9];
    float* dout = (float*)d_out;
    float* ws = (float*)d_ws;

    // o_big region: Ah/Al -> px + pxb + y2 + y1
    unsigned short* Ah = (unsigned short*)(ws + o_big);
    unsigned short* Al = Ah + (size_t)MTOT * DV_;
    float* px  = ws + o_big;
    unsigned short* pxb = (unsigned short*)(ws + o_big + 4718592);
    unsigned short* y2h = (unsigned short*)(ws + o_big + 7077888);
    unsigned short* y2l = y2h + NPX;
    unsigned short* y1h = (unsigned short*)(ws + o_big + 11796480);
    unsigned short* y1l = y1h + NPX;
    // o_c1 region: C1h/C1l -> accb + x1
    unsigned short* C1h = (unsigned short*)(ws + o_c1);
    unsigned short* C1l = C1h + (size_t)MTOT * D1_;
    float* accb = ws + o_c1;
    float* x1   = ws + o_c1 + 4718592;
    // o_c2 region: C2 -> x2f
    float* C2  = ws + o_c2;
    float* x2f = ws + o_c2;
    // weights
    unsigned short* wsS = (unsigned short*)(ws + o_w);
    unsigned short *W1h = wsS + sw_w1h, *W1l = wsS + sw_w1l;
    unsigned short *W2h = wsS + sw_w2h, *W2l = wsS + sw_w2l;
    unsigned short *g1h = wsS + sw_g1h, *g1l = wsS + sw_g1l;
    unsigned short *g2h = wsS + sw_g2h, *g2l = wsS + sw_g2l;
    float* S   = ws + o_S;
    float* den = ws + o_den;

    // init + splits
    k_init<<<MTOT / 256, 256, 0, stream>>>(den, seq, S);
    k_split_in<<<16384, 256, 0, stream>>>(inputs, Ah, Al);
    k_split_w<<<576, 256, 0, stream>>>(w1, w2, W1h, W1l, W2h, W2l);
    k_padgw_t<<<dim3(144, 2), 256, 0, stream>>>(gw1, gw2, g1h, g1l, g2h, g2l);

    // MLP via split-bf16x3 MFMA (prefetched)
    gemm_mfma_nt<<<dim3(D1_ / 128, MTOT / 128), 256, 0, stream>>>(
        Ah, Al, DV_, W1h, W1l, DV_, b1, nullptr, C1h, C1l, D1_, DV_);
    gemm_mfma_nt<<<dim3(1, MTOT / 128), 256, 0, stream>>>(
        C1h, C1l, D1_, W2h, W2l, D1_, b2, C2, nullptr, nullptr, D2_, D1_);

    // expmap0 (px/pxb overwrite Ah region — Ah dead after MLP1)
    k_proj<<<MTOT, 256, 0, stream>>>(C2, inputs, px, pxb);

    // zero correction accumulator (overwrites C1 — dead after MLP2)
    k_zero<<<4096, 256, 0, stream>>>(accb, NPX);

    // valid column sums
    k_ssum<<<dim3(BB, TT / 32), 256, 0, stream>>>(px, seq, S);

    // Lorentz similarity via bf16 MFMA, upper triangle (prefetched, unspilled)
    k_xy_mfma<<<dim3(TT / 128, TT / 128, BB), 256, 0, stream>>>(pxb, px, seq, den, accb);

    // Y1 = (S + corr + diag)/den -> split bf16
    k_y1<<<(int)(NPX / 256), 256, 0, stream>>>(accb, S, den, seq, px, y1h, y1l);

    // disadj @ px via dual scan -> split bf16
    k_band<<<dim3(TT / CH, BB), 256, 0, stream>>>(px, y2h, y2l);

    // graph-conv projections via MFMA
    gemm_mfma_nt<<<dim3(1, MTOT / 128), 256, 0, stream>>>(
        y1h, y1l, DHP, g1h, g1l, DHP, nullptr, x1, nullptr, nullptr, DG_, DHP);
    gemm_mfma_nt<<<dim3(1, MTOT / 128), 256, 0, stream>>>(
        y2h, y2l, DHP, g2h, g2l, DHP, nullptr, x2f, nullptr, nullptr, DG_, DHP);

    // frame_prob + MIL
    k_frame<<<MTOT / 4, 256, 0, stream>>>(x1, x2f, cls_w, cls_b, dout);
    k_clas<<<BB, 1024, 0, stream>>>(seq, dout);
}

// Round 8
// 585.627 us; speedup vs baseline: 3.0761x; 1.0223x over previous
//
#include <hip/hip_runtime.h>
#include <math.h>

// ---------------------------------------------------------------- constants
#define BB 8
#define TT 2048
#define DV_ 1024
#define DA_ 128
#define D1_ 512
#define D2_ 128
#define DH_ 257
#define DHP 288            // padded (zeros): divisible by 32 for MFMA K-chunks
#define DG_ 128
#define MTOT (BB*TT)       // 16384 rows
#define NPX ((size_t)MTOT*DHP)

#define NEGS 0.01f
#define INV_E 0.36787944117144233f
#define CH 64              // scan chunk rows
#define HALO 128           // r^128 ~ 3.5e-21: carry beyond halo is sub-eps

// ---------------------------------------------------------------- workspace
static const size_t o_big = 0;                     // 16,777,216 f
static const size_t o_c1  = 16777216;              //  8,388,608 f
static const size_t o_c2  = o_c1 + 8388608;        //  2,097,152 f
static const size_t o_w   = o_c2 + 2097152;        //    663,552 f (split weights)
static const size_t o_S   = o_w + 663552;          //      2,304 f
static const size_t o_den = o_S + 2304;            //     16,384 f

// short offsets inside o_w
static const size_t sw_w1h = 0;          // 524,288
static const size_t sw_w1l = 524288;
static const size_t sw_w2h = 1048576;    // 65,536
static const size_t sw_w2l = 1114112;
static const size_t sw_g1h = 1179648;    // 36,864 ([128][288])
static const size_t sw_g1l = 1216512;
static const size_t sw_g2h = 1253376;
static const size_t sw_g2l = 1290240;

typedef __attribute__((ext_vector_type(8))) __bf16 bf16x8;
typedef __attribute__((ext_vector_type(8))) unsigned short u16x8;
typedef __attribute__((ext_vector_type(4))) float f32x4;

__device__ __forceinline__ float diag_w() {
    // identical fp32 ops to the generic path evaluated at xy == 1.0f
    float dd = logf(1.0f + sqrtf(1.0f*1.0f - 1.0f + 1e-7f));
    dd = fminf(fmaxf(dd, 1e-6f), 200.0f);
    float x2 = expf(-dd);
    return expf(x2) - 1.0f;
}

__device__ __forceinline__ unsigned short f2bf(float f) {
    unsigned int u = __float_as_uint(f);
    u += 0x7FFFu + ((u >> 16) & 1u);   // RNE
    return (unsigned short)(u >> 16);
}
__device__ __forceinline__ float bf2f(unsigned short h) {
    return __uint_as_float((unsigned int)h << 16);
}

// two float4 -> (hi,lo) bf16x8 fragments
__device__ __forceinline__ void cvt_split(const float4 v0, const float4 v1,
                                          bf16x8& hv, bf16x8& lv) {
    union { u16x8 u; bf16x8 b; } H, L;
    float vv[8] = {v0.x, v0.y, v0.z, v0.w, v1.x, v1.y, v1.z, v1.w};
#pragma unroll
    for (int e = 0; e < 8; ++e) {
        unsigned short hh = f2bf(vv[e]);
        H.u[e] = hh;
        L.u[e] = f2bf(vv[e] - bf2f(hh));
    }
    hv = H.b; lv = L.b;
}

// ---------------------------------------------------------------- utilities
__global__ void k_zero(float* __restrict__ p, size_t n) {
    size_t i = (size_t)blockIdx.x * 256 + threadIdx.x;
    size_t stride = (size_t)gridDim.x * 256;
    for (; i < n; i += stride) p[i] = 0.f;
}

// den init + S zero (merged)
__global__ void k_init(float* __restrict__ den, const int* __restrict__ seq,
                       float* __restrict__ S) {
    int r = blockIdx.x * 256 + threadIdx.x;   // 16384 total
    den[r] = (float)seq[r >> 11] + diag_w();
    if (r < BB * DHP) S[r] = 0.f;
}

// w1 + w2 fp32 -> (hi,lo) bf16 split in one launch
__global__ void k_split_w(const float* __restrict__ w1, const float* __restrict__ w2,
                          unsigned short* __restrict__ h1, unsigned short* __restrict__ l1,
                          unsigned short* __restrict__ h2, unsigned short* __restrict__ l2) {
    size_t i = ((size_t)blockIdx.x * 256 + threadIdx.x) * 4;
    const float* src; unsigned short *h, *l; size_t o;
    if (i < (size_t)D1_ * DV_) { src = w1; h = h1; l = l1; o = i; }
    else {
        o = i - (size_t)D1_ * DV_;
        if (o >= (size_t)D2_ * D1_) return;
        src = w2; h = h2; l = l2;
    }
    float4 v = *(const float4*)(src + o);
    ushort4 hv, lv;
    hv.x = f2bf(v.x); lv.x = f2bf(v.x - bf2f(hv.x));
    hv.y = f2bf(v.y); lv.y = f2bf(v.y - bf2f(hv.y));
    hv.z = f2bf(v.z); lv.z = f2bf(v.z - bf2f(hv.z));
    hv.w = f2bf(v.w); lv.w = f2bf(v.w - bf2f(hv.w));
    *(ushort4*)(h + o) = hv;
    *(ushort4*)(l + o) = lv;
}

// gw1/gw2 [257][128] -> transposed, padded, split [128][288]; blockIdx.y picks
__global__ void k_padgw_t(const float* __restrict__ g1, const float* __restrict__ g2,
                          unsigned short* __restrict__ h1, unsigned short* __restrict__ l1,
                          unsigned short* __restrict__ h2, unsigned short* __restrict__ l2) {
    int i = blockIdx.x * 256 + threadIdx.x;   // DG*DHP = 36864
    if (i >= DG_ * DHP) return;
    const float* g = blockIdx.y ? g2 : g1;
    unsigned short* th = blockIdx.y ? h2 : h1;
    unsigned short* tl = blockIdx.y ? l2 : l1;
    int c = i / DHP, k = i - c * DHP;
    float v = (k < DH_) ? g[k * DG_ + c] : 0.f;
    unsigned short hh = f2bf(v);
    th[i] = hh;
    tl[i] = f2bf(v - bf2f(hh));
}

// ------------------------------------------------- MLP1: fused-split MFMA GEMM
// A = inputs fp32 (row stride 1152, first 1024 cols), split to bf16 hi/lo
// in-register. B = W1 pre-split. XCD swizzle: the 4 column-tiles of one
// 128-row A-panel get blockIdx = p (mod 8) with adjacent slots -> same XCD,
// panel read from HBM once, then L2-resident (r7: 4 XCDs each fetched it:
// FETCH 234 MB vs 64 ideal).
#define M1_LOADA(S, k0) \
    _Pragma("unroll") \
    for (int t = 0; t < 4; ++t) { \
        const float* ap = A + (size_t)(r0 + t*16 + m) * 1152 + (k0) + q*8; \
        ar##S[t][0] = *(const float4*)ap; \
        ar##S[t][1] = *(const float4*)(ap + 4); \
    }
#define M1_LOADB(S, k0) \
    _Pragma("unroll") \
    for (int t = 0; t < 4; ++t) { \
        size_t bo = (size_t)(c0 + t*16 + m) * DV_ + (k0) + q*8; \
        bh##S[t] = *(const bf16x8*)(Bh + bo); \
        bl##S[t] = *(const bf16x8*)(Bl + bo); \
    }
#define M1_MFMA(S) \
    _Pragma("unroll") \
    for (int mi = 0; mi < 4; ++mi) { \
        bf16x8 ahv, alv; \
        cvt_split(ar##S[mi][0], ar##S[mi][1], ahv, alv); \
        _Pragma("unroll") \
        for (int nj = 0; nj < 4; ++nj) { \
            acc[mi][nj] = __builtin_amdgcn_mfma_f32_16x16x32_bf16(ahv, bh##S[nj], acc[mi][nj], 0, 0, 0); \
            acc[mi][nj] = __builtin_amdgcn_mfma_f32_16x16x32_bf16(alv, bh##S[nj], acc[mi][nj], 0, 0, 0); \
            acc[mi][nj] = __builtin_amdgcn_mfma_f32_16x16x32_bf16(ahv, bl##S[nj], acc[mi][nj], 0, 0, 0); \
        } \
    }

__global__ __launch_bounds__(256, 1) void gemm_mlp1(
    const float* __restrict__ A,
    const unsigned short* __restrict__ Bh, const unsigned short* __restrict__ Bl,
    const float* __restrict__ bias,
    unsigned short* __restrict__ Ch, unsigned short* __restrict__ Cl)
{
    const int ib = blockIdx.x;               // 512 blocks
    const int x = ib & 7, slot = ib >> 3;    // xcd lane, 64 slots
    const int cc = slot & 3, g = slot >> 2;  // col-tile, panel group
    const int row0 = (x + 8 * g) * 128, col0 = cc * 128;
    const int wave = threadIdx.x >> 6, lane = threadIdx.x & 63;
    const int r0 = row0 + (wave >> 1) * 64, c0 = col0 + (wave & 1) * 64;
    const int q = lane >> 4, m = lane & 15;
    f32x4 acc[4][4];
#pragma unroll
    for (int a = 0; a < 4; ++a)
#pragma unroll
        for (int c = 0; c < 4; ++c) acc[a][c] = (f32x4){0.f, 0.f, 0.f, 0.f};
    float4 ar0[4][2], ar1[4][2];
    bf16x8 bh0[4], bl0[4], bh1[4], bl1[4];
    M1_LOADA(0, 0)
    M1_LOADB(0, 0)
    for (int k0 = 0; k0 + 64 <= DV_; k0 += 64) {
        M1_LOADA(1, k0 + 32)
        M1_LOADB(1, k0 + 32)
        M1_MFMA(0)
        if (k0 + 64 < DV_) {
            M1_LOADA(0, k0 + 64)
            M1_LOADB(0, k0 + 64)
        }
        M1_MFMA(1)
    }
    float bj[4];
#pragma unroll
    for (int nj = 0; nj < 4; ++nj) bj[nj] = bias[c0 + nj*16 + m];
#pragma unroll
    for (int mi = 0; mi < 4; ++mi)
#pragma unroll
        for (int nj = 0; nj < 4; ++nj)
#pragma unroll
            for (int t = 0; t < 4; ++t) {
                int i = r0 + mi*16 + q*4 + t;
                int j = c0 + nj*16 + m;
                float v = acc[mi][nj][t] + bj[nj];
                v = (v >= 0.f) ? v : NEGS * v;
                size_t o = (size_t)i * D1_ + j;
                unsigned short hh = f2bf(v);
                Ch[o] = hh;
                Cl[o] = f2bf(v - bf2f(hh));
            }
}

// ------------------------------------------------- split-bf16x3 MFMA GEMM (NT)
// C = leaky(A*B^T + bias). a*b ~ ah*bh+al*bh+ah*bl (error ~2^-17 rel ~ fp32).
// Register double-buffer prefetch. (256,1): VGPR budget 512 (default clamps
// to 64 -> spill).
#define LOADK(S, k0) \
    _Pragma("unroll") \
    for (int t = 0; t < 4; ++t) { \
        size_t ao = (size_t)(r0 + t*16 + m) * lda + (k0) + q*8; \
        size_t bo = (size_t)(c0 + t*16 + m) * ldb + (k0) + q*8; \
        ah##S[t] = *(const bf16x8*)(Ah + ao); \
        al##S[t] = *(const bf16x8*)(Al + ao); \
        bh##S[t] = *(const bf16x8*)(Bh + bo); \
        bl##S[t] = *(const bf16x8*)(Bl + bo); \
    }
#define MFMAK(S) \
    _Pragma("unroll") \
    for (int mi = 0; mi < 4; ++mi) \
        _Pragma("unroll") \
        for (int nj = 0; nj < 4; ++nj) { \
            acc[mi][nj] = __builtin_amdgcn_mfma_f32_16x16x32_bf16(ah##S[mi], bh##S[nj], acc[mi][nj], 0, 0, 0); \
            acc[mi][nj] = __builtin_amdgcn_mfma_f32_16x16x32_bf16(al##S[mi], bh##S[nj], acc[mi][nj], 0, 0, 0); \
            acc[mi][nj] = __builtin_amdgcn_mfma_f32_16x16x32_bf16(ah##S[mi], bl##S[nj], acc[mi][nj], 0, 0, 0); \
        }

__global__ __launch_bounds__(256, 1) void gemm_mfma_nt(
    const unsigned short* __restrict__ Ah, const unsigned short* __restrict__ Al, int lda,
    const unsigned short* __restrict__ Bh, const unsigned short* __restrict__ Bl, int ldb,
    const float* __restrict__ bias,
    float* __restrict__ Cf, unsigned short* __restrict__ Ch, unsigned short* __restrict__ Cl,
    int N, int K)
{
    const int row0 = blockIdx.y * 128, col0 = blockIdx.x * 128;
    const int wave = threadIdx.x >> 6, lane = threadIdx.x & 63;
    const int r0 = row0 + (wave >> 1) * 64, c0 = col0 + (wave & 1) * 64;
    const int q = lane >> 4, m = lane & 15;
    f32x4 acc[4][4];
#pragma unroll
    for (int a = 0; a < 4; ++a)
#pragma unroll
        for (int c = 0; c < 4; ++c) acc[a][c] = (f32x4){0.f, 0.f, 0.f, 0.f};
    bf16x8 ah0[4], al0[4], bh0[4], bl0[4];
    bf16x8 ah1[4], al1[4], bh1[4], bl1[4];
    LOADK(0, 0)
    int k0 = 0;
    for (; k0 + 64 <= K; k0 += 64) {
        LOADK(1, k0 + 32)
        MFMAK(0)
        if (k0 + 64 < K) { LOADK(0, k0 + 64) }
        MFMAK(1)
    }
    if (k0 < K) { MFMAK(0) }   // odd tail chunk (K=288)
    float bj[4];
#pragma unroll
    for (int nj = 0; nj < 4; ++nj)
        bj[nj] = bias ? bias[c0 + nj*16 + m] : 0.f;
#pragma unroll
    for (int mi = 0; mi < 4; ++mi)
#pragma unroll
        for (int nj = 0; nj < 4; ++nj)
#pragma unroll
            for (int t = 0; t < 4; ++t) {
                int i = r0 + mi*16 + q*4 + t;
                int j = c0 + nj*16 + m;
                float v = acc[mi][nj][t] + bj[nj];
                v = (v >= 0.f) ? v : NEGS * v;
                size_t o = (size_t)i * N + j;
                if (Cf) Cf[o] = v;
                if (Ch) {
                    unsigned short hh = f2bf(v);
                    Ch[o] = hh;
                    Cl[o] = f2bf(v - bf2f(hh));
                }
            }
}

// ------------------------------------------------- xy via bf16 MFMA (upper tri)
// Only observable effect: which pairs pass x2>0.8. Off-diag xy ~1e13 vs band
// [1,1.026]; bf16 error ~1e11 -> classification identical to fp32/f64.
#define XLOAD(S, k0) \
    _Pragma("unroll") \
    for (int t = 0; t < 4; ++t) { \
        af##S[t] = *(const bf16x8*)(base + (size_t)(r0 + t*16 + m) * DHP + (k0) + q*8); \
        bf##S[t] = *(const bf16x8*)(base + (size_t)(c0 + t*16 + m) * DHP + (k0) + q*8); \
    }
#define XMFMA(S) \
    _Pragma("unroll") \
    for (int mi = 0; mi < 4; ++mi) \
        _Pragma("unroll") \
        for (int nj = 0; nj < 4; ++nj) \
            acc[mi][nj] = __builtin_amdgcn_mfma_f32_16x16x32_bf16(af##S[mi], bf##S[nj], acc[mi][nj], 0, 0, 0);

__global__ __launch_bounds__(256, 1) void k_xy_mfma(
    const unsigned short* __restrict__ pxb, const float* __restrict__ px,
    const int* __restrict__ seq, float* __restrict__ den, float* __restrict__ accb)
{
    const int b = blockIdx.z;
    const int bx = blockIdx.x, by = blockIdx.y;
    if (bx < by) return;
    const int nb = seq[b];
    const int row0 = by * 128, col0 = bx * 128;
    if (row0 >= nb || col0 >= nb) return;
    const int wave = threadIdx.x >> 6, lane = threadIdx.x & 63;
    const int r0 = row0 + (wave >> 1) * 64, c0 = col0 + (wave & 1) * 64;
    if (c0 + 63 < r0 || r0 >= nb || c0 >= nb) return;   // wave-uniform exits
    const unsigned short* base = pxb + (size_t)b * TT * DHP;
    const int q = lane >> 4, m = lane & 15;
    f32x4 acc[4][4];
#pragma unroll
    for (int a = 0; a < 4; ++a)
#pragma unroll
        for (int c = 0; c < 4; ++c) acc[a][c] = (f32x4){0.f, 0.f, 0.f, 0.f};
    bf16x8 af0[4], bf0[4], af1[4], bf1[4];
    XLOAD(0, 0)
    int k0 = 0;
    for (; k0 + 64 <= DHP; k0 += 64) {
        XLOAD(1, k0 + 32)
        XMFMA(0)
        if (k0 + 64 < DHP) { XLOAD(0, k0 + 64) }
        XMFMA(1)
    }
    if (k0 < DHP) { XMFMA(0) }
    const float* b32 = px + (size_t)b * TT * DHP;
    float cj[4], ci[4][4];
#pragma unroll
    for (int nj = 0; nj < 4; ++nj) cj[nj] = b32[(size_t)(c0 + nj*16 + m) * DHP];
#pragma unroll
    for (int mi = 0; mi < 4; ++mi)
#pragma unroll
        for (int t = 0; t < 4; ++t) ci[mi][t] = b32[(size_t)(r0 + mi*16 + q*4 + t) * DHP];
#pragma unroll
    for (int mi = 0; mi < 4; ++mi)
#pragma unroll
        for (int nj = 0; nj < 4; ++nj)
#pragma unroll
            for (int t = 0; t < 4; ++t) {
                int i = r0 + mi*16 + q*4 + t;
                int j = c0 + nj*16 + m;
                if (i < j && j < nb) {
                    float xyv = 2.f * ci[mi][t] * cj[nj] - acc[mi][nj][t];
                    float xym = fmaxf(xyv, 1.0f);
                    // xym >= 1.026 => x2 <= 0.798 < 0.8: no correction
                    if (xym < 1.026f) {
                        float dd = logf(xym + sqrtf(xym * xym - 1.0f + 1e-7f));
                        dd = fminf(fmaxf(dd, 1e-6f), 200.0f);
                        float x2v = expf(-dd);
                        if (x2v > 0.8f) {
                            float w = expf(x2v) - 1.0f;
                            atomicAdd(&den[b * TT + i], w);
                            atomicAdd(&den[b * TT + j], w);
                            const float* pi = b32 + (size_t)i * DHP;
                            const float* pj = b32 + (size_t)j * DHP;
                            float* ai = accb + ((size_t)(b * TT + i)) * DHP;
                            float* aj = accb + ((size_t)(b * TT + j)) * DHP;
                            for (int d = 0; d < DHP; ++d) {
                                atomicAdd(&ai[d], w * pj[d]);
                                atomicAdd(&aj[d], w * pi[d]);
                            }
                        }
                    }
                }
            }
}

// ------------------------------------------------- expmap0 (px fp32 + bf16)
__global__ __launch_bounds__(256) void k_proj(
    const float* __restrict__ C2, const float* __restrict__ inputs,
    float* __restrict__ px, unsigned short* __restrict__ pxb)
{
    const int r = blockIdx.x;
    const int tid = threadIdx.x;
    float v = (tid < 128) ? C2[(size_t)r * 128 + tid]
                          : inputs[(size_t)r * 1152 + 1024 + (tid - 128)];
    float sq = v * v;
#pragma unroll
    for (int o = 32; o > 0; o >>= 1) sq += __shfl_down(sq, o, 64);
    __shared__ float wred[4];
    __shared__ float cs[2];
    if ((tid & 63) == 0) wred[tid >> 6] = sq;
    __syncthreads();
    if (tid == 0) {
        float n2 = fmaxf(wred[0] + wred[1] + wred[2] + wred[3], 1e-12f);
        float n = sqrtf(n2);
        cs[0] = coshf(n);
        cs[1] = sinhf(n) / n;
    }
    __syncthreads();
    float sv = cs[1] * v;
    px[(size_t)r * DHP + 1 + tid] = sv;
    pxb[(size_t)r * DHP + 1 + tid] = f2bf(sv);
    if (tid == 0) {
        px[(size_t)r * DHP] = cs[0];
        pxb[(size_t)r * DHP] = f2bf(cs[0]);
    }
    if (tid < DHP - DH_) {   // 31 pad zeros
        px[(size_t)r * DHP + DH_ + tid] = 0.f;
        pxb[(size_t)r * DHP + DH_ + tid] = 0;
    }
}

// ------------------------------------------------- per-batch valid column sum
__global__ __launch_bounds__(256) void k_ssum(
    const float* __restrict__ px, const int* __restrict__ seq,
    float* __restrict__ S)
{
    const int b = blockIdx.x, chunk = blockIdx.y, tid = threadIdx.x;
    const int nb = seq[b];
    const int j0 = chunk * 32;
    const int j1 = (j0 + 32 < nb) ? j0 + 32 : nb;
    float a0 = 0.f, a1 = 0.f;
    const bool hasB = (tid < DHP - 256);
    for (int j = j0; j < j1; ++j) {
        const float* row = px + ((size_t)(b * TT + j)) * DHP;
        a0 += row[tid];
        if (hasB) a1 += row[256 + tid];
    }
    if (j1 > j0) {
        atomicAdd(&S[b * DHP + tid], a0);
        if (hasB) atomicAdd(&S[b * DHP + 256 + tid], a1);
    }
}

// ------------------------------------------------- Y1 = (S + corr + wd*px)/den
// emits split bf16 for the downstream MFMA graph-conv
__global__ void k_y1(const float* __restrict__ accb, const float* __restrict__ S,
                     const float* __restrict__ den, const int* __restrict__ seq,
                     const float* __restrict__ px,
                     unsigned short* __restrict__ yh, unsigned short* __restrict__ yl)
{
    size_t idx = (size_t)blockIdx.x * 256 + threadIdx.x;
    if (idx >= NPX) return;
    int r = (int)(idx / DHP);
    int b = r >> 11, i = r & (TT - 1);
    int d = (int)(idx - (size_t)r * DHP);
    float out = 0.f;
    if (i < seq[b])
        out = (S[b * DHP + d] + accb[idx] + diag_w() * px[idx]) / den[r];
    unsigned short hh = f2bf(out);
    yh[idx] = hh;
    yl[idx] = f2bf(out - bf2f(hh));
}

// ------------------------------------------------- disadj @ px via dual scan
// disadj[i,j] = r^|i-j|: full matvec = fwd + bwd first-order recursions with
// HALO=128 warmup (carry decay r^128 ~ 3.5e-21 — sub-fp32-eps at any px scale).
__global__ __launch_bounds__(256) void k_band(
    const float* __restrict__ px,
    unsigned short* __restrict__ yh, unsigned short* __restrict__ yl)
{
    __shared__ float Fs[CH][DHP];   // 73,728 B
    const int b = blockIdx.y;
    const int i0 = blockIdx.x * CH;
    const int tid = threadIdx.x;
    const bool hasB = (tid < DHP - 256);
    const float r = expf(-INV_E);
    const float* base = px + (size_t)b * TT * DHP;

    // forward scan with left halo
    {
        const int jlo = (i0 - HALO > 0) ? i0 - HALO : 0;
        float LA = 0.f, LB = 0.f;
        for (int j = jlo; j < i0 + CH; ++j) {
            const float* row = base + (size_t)j * DHP;
            LA = fmaf(r, LA, row[tid]);
            if (hasB) LB = fmaf(r, LB, row[256 + tid]);
            if (j >= i0) {
                Fs[j - i0][tid] = LA;
                if (hasB) Fs[j - i0][256 + tid] = LB;
            }
        }
    }
    __syncthreads();
    // backward scan with right halo; emit y = F + G - px
    {
        const int jhi = (i0 + CH - 1 + HALO < TT - 1) ? i0 + CH - 1 + HALO : TT - 1;
        float RA = 0.f, RB = 0.f;
        for (int j = jhi; j >= i0; --j) {
            const float* row = base + (size_t)j * DHP;
            float pa = row[tid];
            float pb = hasB ? row[256 + tid] : 0.f;
            RA = fmaf(r, RA, pa);
            if (hasB) RB = fmaf(r, RB, pb);
            if (j < i0 + CH) {
                size_t o = ((size_t)(b * TT + j)) * DHP + tid;
                float ya = Fs[j - i0][tid] + RA - pa;
                unsigned short hh = f2bf(ya);
                yh[o] = hh; yl[o] = f2bf(ya - bf2f(hh));
                if (hasB) {
                    float yb = Fs[j - i0][256 + tid] + RB - pb;
                    size_t ob = o + 256;
                    unsigned short h2 = f2bf(yb);
                    yh[ob] = h2; yl[ob] = f2bf(yb - bf2f(h2));
                }
            }
        }
    }
}

// ------------------------------------------------- frame_prob
__global__ __launch_bounds__(256) void k_frame(
    const float* __restrict__ x1, const float* __restrict__ x2f,
    const float* __restrict__ cls_w, const float* __restrict__ cls_b,
    float* __restrict__ dout)
{
    const int r = blockIdx.x * 4 + (threadIdx.x >> 6);
    const int lane = threadIdx.x & 63;
    float s = 0.f;
#pragma unroll
    for (int t = 0; t < 2; ++t) {
        int g = lane + t * 64;
        float cw1 = cls_w[g];
        if (g == 0) cw1 = -cw1;      // signs: only dim 0 negated
        s += x1[(size_t)r * DG_ + g] * cw1;
        s += x2f[(size_t)r * DG_ + g] * cls_w[DG_ + g];
    }
#pragma unroll
    for (int o = 32; o > 0; o >>= 1) s += __shfl_down(s, o, 64);
    if (lane == 0) dout[8 + r] = 2.0f + 2.0f * s + cls_b[0];
}

// ------------------------------------------------- top-k MIL (bitonic sort)
__global__ __launch_bounds__(1024) void k_clas(
    const int* __restrict__ seq, float* __restrict__ dout)
{
    __shared__ float s[TT];
    const int b = blockIdx.x, tid = threadIdx.x;
    const int nb = seq[b];
    for (int t = tid; t < TT; t += 1024)
        s[t] = (t < nb) ? dout[8 + b * TT + t] : -1e30f;
    __syncthreads();
    for (int k = 2; k <= TT; k <<= 1)
        for (int j = k >> 1; j > 0; j >>= 1) {
            for (int i = tid; i < TT; i += 1024) {
                int ixj = i ^ j;
                if (ixj > i) {
                    float a = s[i], c = s[ixj];
                    bool descBlk = ((i & k) == 0);
                    if (descBlk ? (a < c) : (a > c)) { s[i] = c; s[ixj] = a; }
                }
            }
            __syncthreads();
        }
    const int kk = nb / 16 + 1;
    float part = 0.f;
    for (int t = tid; t < kk; t += 1024) part += s[t];
#pragma unroll
    for (int o = 32; o > 0; o >>= 1) part += __shfl_down(part, o, 64);
    __shared__ float wred[16];
    if ((tid & 63) == 0) wred[tid >> 6] = part;
    __syncthreads();
    if (tid == 0) {
        float mil = 0.f;
#pragma unroll
        for (int t = 0; t < 16; ++t) mil += wred[t];
        mil /= (float)kk;
        dout[b] = 1.f / (1.f + expf(-mil));
    }
}

// ---------------------------------------------------------------- launch
extern "C" void kernel_launch(void* const* d_in, const int* in_sizes, int n_in,
                              void* d_out, int out_size, void* d_ws, size_t ws_size,
                              hipStream_t stream) {
    (void)in_sizes; (void)n_in; (void)out_size; (void)ws_size;
    const float* inputs = (const float*)d_in[0];
    const int*   seq    = (const int*)d_in[1];
    const float* w1     = (const float*)d_in[2];
    const float* b1     = (const float*)d_in[3];
    const float* w2     = (const float*)d_in[4];
    const float* b2     = (const float*)d_in[5];
    const float* gw1    = (const float*)d_in[6];
    const float* gw2    = (const float*)d_in[7];
    const float* cls_w  = (const float*)d_in[8];
    const float* cls_b  = (const float*)d_in[9];
    float* dout = (float*)d_out;
    float* ws = (float*)d_ws;

    // o_big region: px + pxb + y2 + y1
    float* px  = ws + o_big;
    unsigned short* pxb = (unsigned short*)(ws + o_big + 4718592);
    unsigned short* y2h = (unsigned short*)(ws + o_big + 7077888);
    unsigned short* y2l = y2h + NPX;
    unsigned short* y1h = (unsigned short*)(ws + o_big + 11796480);
    unsigned short* y1l = y1h + NPX;
    // o_c1 region: C1h/C1l -> accb + x1
    unsigned short* C1h = (unsigned short*)(ws + o_c1);
    unsigned short* C1l = C1h + (size_t)MTOT * D1_;
    float* accb = ws + o_c1;
    float* x1   = ws + o_c1 + 4718592;
    // o_c2 region: C2 -> x2f
    float* C2  = ws + o_c2;
    float* x2f = ws + o_c2;
    // weights
    unsigned short* wsS = (unsigned short*)(ws + o_w);
    unsigned short *W1h = wsS + sw_w1h, *W1l = wsS + sw_w1l;
    unsigned short *W2h = wsS + sw_w2h, *W2l = wsS + sw_w2l;
    unsigned short *g1h = wsS + sw_g1h, *g1l = wsS + sw_g1l;
    unsigned short *g2h = wsS + sw_g2h, *g2l = wsS + sw_g2l;
    float* S   = ws + o_S;
    float* den = ws + o_den;

    // init + splits
    k_init<<<MTOT / 256, 256, 0, stream>>>(den, seq, S);
    k_split_w<<<576, 256, 0, stream>>>(w1, w2, W1h, W1l, W2h, W2l);
    k_padgw_t<<<dim3(144, 2), 256, 0, stream>>>(gw1, gw2, g1h, g1l, g2h, g2l);

    // MLP1: fused fp32-split MFMA GEMM, XCD-swizzled
    gemm_mlp1<<<512, 256, 0, stream>>>(inputs, W1h, W1l, b1, C1h, C1l);
    // MLP2
    gemm_mfma_nt<<<dim3(1, MTOT / 128), 256, 0, stream>>>(
        C1h, C1l, D1_, W2h, W2l, D1_, b2, C2, nullptr, nullptr, D2_, D1_);

    // expmap0
    k_proj<<<MTOT, 256, 0, stream>>>(C2, inputs, px, pxb);

    // zero correction accumulator (overwrites C1 — dead after MLP2)
    k_zero<<<4096, 256, 0, stream>>>(accb, NPX);

    // valid column sums
    k_ssum<<<dim3(BB, TT / 32), 256, 0, stream>>>(px, seq, S);

    // Lorentz similarity via bf16 MFMA, upper triangle
    k_xy_mfma<<<dim3(TT / 128, TT / 128, BB), 256, 0, stream>>>(pxb, px, seq, den, accb);

    // Y1 = (S + corr + diag)/den -> split bf16
    k_y1<<<(int)(NPX / 256), 256, 0, stream>>>(accb, S, den, seq, px, y1h, y1l);

    // disadj @ px via dual scan -> split bf16
    k_band<<<dim3(TT / CH, BB), 256, 0, stream>>>(px, y2h, y2l);

    // graph-conv projections via MFMA
    gemm_mfma_nt<<<dim3(1, MTOT / 128), 256, 0, stream>>>(
        y1h, y1l, DHP, g1h, g1l, DHP, nullptr, x1, nullptr, nullptr, DG_, DHP);
    gemm_mfma_nt<<<dim3(1, MTOT / 128), 256, 0, stream>>>(
        y2h, y2l, DHP, g2h, g2l, DHP, nullptr, x2f, nullptr, nullptr, DG_, DHP);

    // frame_prob + MIL
    k_frame<<<MTOT / 4, 256, 0, stream>>>(x1, x2f, cls_w, cls_b, dout);
    k_clas<<<BB, 1024, 0, stream>>>(seq, dout);
}